// Round 7
// baseline (535.765 us; speedup 1.0000x reference)
//
#include <hip/hip_runtime.h>

// ---------------------------------------------------------------------------
// Round 26: G=32 gather + INDEPENDENT ACCUMULATORS + col prefetch.
//  R25 post-mortem: VGPR=12 again -> compiler serialized the 4 row loads
//  (single a0/a1 accumulation chain). R19 pipelined BECAUSE it had 16
//  independent accumulator chains. Fix: s0..s7 (one pair per row-load temp)
//  + next-col prefetch rotation issued after the row loads. Everything else
//  (build_a / build_b / transform / dot, layout, epilogue) unchanged.
// ---------------------------------------------------------------------------

#define CHP 4096  // edges per partition block (both directions)
#define BC 6144   // bucket capacity (E[cnt]=5120, sigma=72 -> 14-sigma margin)

__device__ __forceinline__ float b2f(unsigned short u) {
    union { unsigned int i; float f; } v; v.i = ((unsigned int)u) << 16; return v.f;
}
__device__ __forceinline__ unsigned short f2b(float f) {
    union { float f; unsigned int i; } v; v.f = f;
    unsigned int i = v.i;
    return (unsigned short)((i + 0x7FFFu + ((i >> 16) & 1u)) >> 16);  // RNE
}
__device__ __forceinline__ float2 bf2(unsigned int w) {   // unpack 2 bf16
    union { unsigned int i; float f; } lo, hi;
    lo.i = w << 16; hi.i = w & 0xFFFF0000u;
    return make_float2(lo.f, hi.f);
}
__device__ __forceinline__ unsigned int pk2(float a, float b) {
    return (unsigned int)f2b(a) | ((unsigned int)f2b(b) << 16);
}
__device__ __forceinline__ float ulo(unsigned int w) {
    union { unsigned int i; float f; } v; v.i = w << 16; return v.f;
}
__device__ __forceinline__ float uhi(unsigned int w) {
    union { unsigned int i; float f; } v; v.i = w & 0xFFFF0000u; return v.f;
}

// ---- build_a: [0,np) dual-dir partition | movie_init | wt | user cvt ------

__global__ __launch_bounds__(256) void build_a(
    int np,
    const int* __restrict__ src, const int* __restrict__ dst, int E,
    int nbu, int nbm, int* __restrict__ bfu, int* __restrict__ bfm,
    int* __restrict__ pu, int* __restrict__ pm,
    const float* __restrict__ movie_x, const float* __restrict__ wm,
    const float* __restrict__ bm, const float* __restrict__ memb,
    unsigned short* __restrict__ xmB, int M,
    const float* __restrict__ llw, const float* __restrict__ lrw,
    float* __restrict__ wTl, float* __restrict__ wTr,
    const float* __restrict__ uemb, unsigned short* __restrict__ buB, int n4u) {
    __shared__ int2 stag[CHP];           // 32 KB ordered staging (per direction)
    __shared__ int hist[512];
    __shared__ int scn[512];
    __shared__ int gb[400];
    __shared__ int lst[400];
    int t = threadIdx.x;
    int b = blockIdx.x;
    if (b < np) {
        // ---- one chunk, both directions; edges held in registers ----
        int c0 = b * CHP, lim = min(c0 + CHP, E), cnt = lim - c0;
        int ks[16], vs[16];
#pragma unroll
        for (int i = 0; i < 16; ++i) {
            int e = c0 + t + i * 256;
            if (e < lim) { ks[i] = src[e]; vs[i] = dst[e]; }
            else { ks[i] = 0; vs[i] = 0; }
        }
        for (int dir = 0; dir < 2; ++dir) {
            const int NB = dir ? nbm : nbu;
            const int SHIFT = dir ? 7 : 8;
            int* bf = dir ? bfm : bfu;
            int* P  = dir ? pm  : pu;
            __syncthreads();   // protect stag/hist reuse from previous dir
            for (int i = t; i < 512; i += 256) hist[i] = 0;
            __syncthreads();
#pragma unroll
            for (int i = 0; i < 16; ++i) {
                if (t + i * 256 < cnt) {
                    int k = dir ? vs[i] : ks[i];
                    atomicAdd(&hist[k >> SHIFT], 1);
                }
            }
            __syncthreads();
            scn[t] = hist[t]; scn[t + 256] = hist[t + 256];
            __syncthreads();
            for (int off = 1; off < 512; off <<= 1) {
                int v0 = scn[t],  a0 = (t >= off) ? scn[t - off] : 0;
                int i1 = t + 256;
                int v1 = scn[i1], a1 = scn[i1 - off];
                __syncthreads();
                scn[t] = v0 + a0; scn[i1] = v1 + a1;
                __syncthreads();
            }
            for (int i = t; i < NB; i += 256) {
                int c = hist[i];
                lst[i] = scn[i] - c;
                int r = c ? atomicAdd(&bf[i], c) : 0;
                if (r < 0) r = 0;
                if (r + c > BC) r = BC - c;
                gb[i] = i * BC + r;
            }
            __syncthreads();
            for (int i = t; i < 512; i += 256) hist[i] = (i < NB) ? lst[i] : 0;
            __syncthreads();
#pragma unroll
            for (int i = 0; i < 16; ++i) {
                if (t + i * 256 < cnt) {
                    int k = dir ? vs[i] : ks[i];
                    int v = dir ? ks[i] : vs[i];
                    int bk = k >> SHIFT;
                    int pos = atomicAdd(&hist[bk], 1);
                    int packed = dir ? ((v << 7) | (k & 127)) : ((v << 8) | (k & 255));
                    stag[pos] = make_int2(packed, bk);
                }
            }
            __syncthreads();
            for (int j = t; j < cnt; j += 256) {
                int2 s = stag[j];
                P[gb[s.y] + (j - lst[s.y])] = s.x;
            }
        }
        return;
    }
    int lb = b - np;
    if (lb < 1024) {
        float* w_s = (float*)stag;   // 64*21 floats
        for (int i = t; i < 64 * 20; i += 256) {
            int h = i / 20, f = i % 20;
            w_s[h * 21 + f] = wm[i];
        }
        __syncthreads();
        int lane = t & 63;
        float bias = bm[lane];
        int nw = (1024 * 256) >> 6;
        int w  = (lb * 256 + t) >> 6;
        for (int m = w; m < M; m += nw) {
            float fv  = (lane < 20) ? movie_x[m * 20 + lane] : 0.0f;
            float acc = bias + memb[m * 64 + lane];
#pragma unroll
            for (int f = 0; f < 20; ++f) {
                float xv = __shfl(fv, f, 64);
                acc += xv * w_s[lane * 21 + f];
            }
            xmB[m * 64 + lane] = f2b(acc);
        }
    } else if (lb < 1088) {
        int i = (lb - 1024) * 256 + t;
        int s = i >> 12, rem = i & 4095, k = rem >> 6, h = rem & 63;
        wTl[i] = llw[s * 4096 + h * 64 + k];
        wTr[i] = lrw[s * 4096 + h * 64 + k];
    } else {
        int i0 = ((lb - 1088) * 256 + t) * 4;
#pragma unroll
        for (int k = 0; k < 4; ++k) {
            int i = i0 + k;
            if (i < n4u) {
                float4 v = ((const float4*)uemb)[i];
                ushort4 o;
                o.x = f2b(v.x); o.y = f2b(v.y); o.z = f2b(v.z); o.w = f2b(v.w);
                ((ushort4*)buB)[i] = o;
            }
        }
    }
}

// ---- transform tiles: 128-node tiles, 4x8/thread, XsT bf16, W fp32 in LDS -
// LDS floats: XsT uint[64][68] = 4352 | WA[4096] | WS[4096]  (50176 B)

__device__ __forceinline__ void transform_tiles(
    int tile0, int stride, int ntiles,
    unsigned short* XsT, float* WA, float* WS,
    const unsigned short* __restrict__ X, const float* __restrict__ wA,
    const float* __restrict__ wS, const float* __restrict__ bS,
    unsigned short* __restrict__ A, unsigned short* __restrict__ S, int n) {
    int tid = threadIdx.x;
    for (int i = tid; i < 4096; i += 256) { WA[i] = wA[i]; WS[i] = wS[i]; }
    int hg = tid & 7, ng = tid >> 3;       // 8 col-groups x 32 row-groups
    int h0 = hg * 8, nA = ng * 4;
    float4 b0 = *(const float4*)&bS[h0];
    float4 b1 = *(const float4*)&bS[h0 + 4];
    float bias[8] = {b0.x, b0.y, b0.z, b0.w, b1.x, b1.y, b1.z, b1.w};
    unsigned int* XsT32 = (unsigned int*)XsT;   // pitch 68 uints per k row

    for (int tile = tile0; tile < ntiles; tile += stride) {
        int node0 = tile * 128;
        __syncthreads();   // prev-iter reads done; W visible on first iter
        for (int it = tid; it < 512; it += 256) {
            int p = it & 63, c = it >> 6;
            int g0 = node0 + 2 * p, g1 = g0 + 1;
            uint4 av = make_uint4(0, 0, 0, 0), bv = make_uint4(0, 0, 0, 0);
            if (g0 < n) av = *(const uint4*)(X + (size_t)g0 * 64 + c * 8);
            if (g1 < n) bv = *(const uint4*)(X + (size_t)g1 * 64 + c * 8);
            unsigned int aw[4] = {av.x, av.y, av.z, av.w};
            unsigned int bw[4] = {bv.x, bv.y, bv.z, bv.w};
#pragma unroll
            for (int j = 0; j < 8; ++j) {
                int w = j >> 1;
                unsigned int o = (j & 1)
                    ? ((aw[w] >> 16) | (bw[w] & 0xFFFF0000u))
                    : ((aw[w] & 0xFFFFu) | (bw[w] << 16));
                XsT32[(c * 8 + j) * 68 + p] = o;
            }
        }
        __syncthreads();
        float accA[4][8], accS[4][8];
#pragma unroll
        for (int r = 0; r < 4; ++r)
#pragma unroll
            for (int c = 0; c < 8; ++c) { accA[r][c] = 0.0f; accS[r][c] = 0.0f; }
#pragma unroll 4
        for (int k = 0; k < 64; ++k) {
            ushort4 xv = *(const ushort4*)(XsT + k * 136 + nA);
            float xr[4] = {b2f(xv.x), b2f(xv.y), b2f(xv.z), b2f(xv.w)};
            float4 a0 = *(const float4*)&WA[k * 64 + h0];
            float4 a1 = *(const float4*)&WA[k * 64 + h0 + 4];
            float4 s0 = *(const float4*)&WS[k * 64 + h0];
            float4 s1 = *(const float4*)&WS[k * 64 + h0 + 4];
            float wa[8] = {a0.x, a0.y, a0.z, a0.w, a1.x, a1.y, a1.z, a1.w};
            float ws[8] = {s0.x, s0.y, s0.z, s0.w, s1.x, s1.y, s1.z, s1.w};
#pragma unroll
            for (int r = 0; r < 4; ++r)
#pragma unroll
                for (int c = 0; c < 8; ++c) {
                    accA[r][c] += xr[r] * wa[c];
                    accS[r][c] += xr[r] * ws[c];
                }
        }
#pragma unroll
        for (int r = 0; r < 4; ++r) {
            int gi = node0 + nA + r;
            if (gi < n) {
                uint4 oa, os;
                oa.x = pk2(accA[r][0], accA[r][1]); oa.y = pk2(accA[r][2], accA[r][3]);
                oa.z = pk2(accA[r][4], accA[r][5]); oa.w = pk2(accA[r][6], accA[r][7]);
                os.x = pk2(accS[r][0] + bias[0], accS[r][1] + bias[1]);
                os.y = pk2(accS[r][2] + bias[2], accS[r][3] + bias[3]);
                os.z = pk2(accS[r][4] + bias[4], accS[r][5] + bias[5]);
                os.w = pk2(accS[r][6] + bias[6], accS[r][7] + bias[7]);
                *(uint4*)(A + (size_t)gi * 64 + h0) = oa;
                *(uint4*)(S + (size_t)gi * 64 + h0) = os;
            }
        }
    }
}

// ---- fine CSR body --------------------------------------------------------

template <int NPB, int SH, typename CT>
__device__ __forceinline__ void fine_body(
    int b, int* c, int* sc, const int* __restrict__ part,
    const int* __restrict__ cnt_arr,
    int2* __restrict__ rp2, CT* __restrict__ col, int n) {
    int cnt = min(cnt_arr[b], BC);
    int pb = b * BC;
    int t = threadIdx.x;
    c[t] = 0;
    __syncthreads();
    const int mask = NPB - 1;
    for (int j = t; j < cnt; j += 256)
        atomicAdd(&c[part[pb + j] & mask], 1);
    __syncthreads();
    int own = c[t];
    sc[t] = own;
    __syncthreads();
    for (int off = 1; off < 256; off <<= 1) {
        int val = sc[t];
        int add = (t >= off) ? sc[t - off] : 0;
        __syncthreads();
        sc[t] = val + add;
        __syncthreads();
    }
    int start = pb + sc[t] - own;
    int node = b * NPB + t;
    if (t < NPB && node < n) rp2[node] = make_int2(start, start + own);
    __syncthreads();
    c[t] = start;
    __syncthreads();
    for (int j = t; j < cnt; j += 256) {
        int p = part[pb + j];
        int off = atomicAdd(&c[p & mask], 1);
        col[off] = (CT)(((unsigned)p) >> SH);
    }
}

#define TBM 256   // movie transform blocks
#define TBU 512   // user transform blocks
#define SMEMF (4352 + 4096 + 4096)   // floats: XsT 17408 B + WA 16 KB + WS 16 KB = 50176 B

// ---- build_b: [0, nbm+nbu) fine CSR | +TBM movie transform | +TBU user ----

__global__ __launch_bounds__(256) void build_b(
    int nbm, int nbu, int ntm, int ntu,
    const int* __restrict__ pm, const int* __restrict__ cm,
    int2* __restrict__ rp2_m, int* __restrict__ col_m, int M,
    const int* __restrict__ pu, const int* __restrict__ cu,
    int2* __restrict__ rp2_u, unsigned short* __restrict__ col_u, int U,
    const unsigned short* __restrict__ xM, const float* __restrict__ wAM,
    const float* __restrict__ wSM, const float* __restrict__ bSM,
    unsigned short* __restrict__ AM, unsigned short* __restrict__ SM,
    const unsigned short* __restrict__ xU, const float* __restrict__ wAU,
    const float* __restrict__ wSU, const float* __restrict__ bSU,
    unsigned short* __restrict__ AU, unsigned short* __restrict__ SU) {
    __shared__ float smem[SMEMF];
    int b = blockIdx.x;
    if (b < nbm) {
        fine_body<128, 7, int>(b, (int*)smem, (int*)smem + 256, pm, cm, rp2_m, col_m, M);
        return;
    }
    b -= nbm;
    if (b < nbu) {
        fine_body<256, 8, unsigned short>(b, (int*)smem, (int*)smem + 256, pu, cu, rp2_u, col_u, U);
        return;
    }
    b -= nbu;
    unsigned short* XsT = (unsigned short*)smem;
    float* WA = smem + 4352; float* WS = WA + 4096;
    if (b < TBM) transform_tiles(b, TBM, ntm, XsT, WA, WS, xM, wAM, wSM, bSM, AM, SM, M);
    else transform_tiles(b - TBM, TBU, ntu, XsT, WA, WS, xU, wAU, wSU, bSU, AU, SU, U);
}

// ---- standalone transform (layer 1) ---------------------------------------

__global__ __launch_bounds__(256) void transform_dual(
    int ntm, int ntu,
    const unsigned short* __restrict__ xM, const float* __restrict__ wAM,
    const float* __restrict__ wSM, const float* __restrict__ bSM,
    unsigned short* __restrict__ AM, unsigned short* __restrict__ SM, int M,
    const unsigned short* __restrict__ xU, const float* __restrict__ wAU,
    const float* __restrict__ wSU, const float* __restrict__ bSU,
    unsigned short* __restrict__ AU, unsigned short* __restrict__ SU, int U) {
    __shared__ float smem[SMEMF];
    unsigned short* XsT = (unsigned short*)smem;
    float* WA = smem + 4352; float* WS = WA + 4096;
    int b = blockIdx.x;
    if (b < TBM) transform_tiles(b, TBM, ntm, XsT, WA, WS, xM, wAM, wSM, bSM, AM, SM, M);
    else transform_tiles(b - TBM, TBU, ntu, XsT, WA, WS, xU, wAU, wSU, bSU, AU, SU, U);
}

// ---- half-per-edge gather, independent accumulators -----------------------
// Wave = 2 halves x 32 lanes; half owns one edge of each pair; lane owns a
// feature PAIR (uint = 2 bf16). Per 8-edge iter: 4 row loads into r0..r3,
// accumulated into 8 INDEPENDENT chains s0..s7 (this is what lets the
// compiler batch the loads - R19 evidence), next col vector prefetched
// after the row loads issue. Epilogue: 3 adds + 2 shfl_xor(32).

template <int U16>
__device__ __forceinline__ void gather_body(
    int b, const int2* __restrict__ rp2,
    const int* __restrict__ coli, const unsigned short* __restrict__ colu,
    const unsigned short* __restrict__ A, const unsigned short* __restrict__ S,
    unsigned short* __restrict__ out, int n, int do_relu) {
    int node = __builtin_amdgcn_readfirstlane((b * 256 + (int)threadIdx.x) >> 6);
    if (node >= n) return;
    int lane = (int)threadIdx.x & 63;
    int half = lane >> 5;
    unsigned qoff = ((unsigned)(lane & 31)) << 2;   // byte offset of my pair
    unsigned sh16 = ((unsigned)half) << 4;          // 0 or 16 (U16 id select)
    int2 be = rp2[node];
    int beg = __builtin_amdgcn_readfirstlane(be.x);
    int end = __builtin_amdgcn_readfirstlane(be.y);
    const char* Ab = (const char*)A;
    float s0 = 0, s1 = 0, s2 = 0, s3 = 0, s4 = 0, s5 = 0, s6 = 0, s7 = 0;
    int j = beg;

    // single edge (both halves load same row; only half 0 accumulates)
#define ONE1(idv) do { \
        unsigned _r = *(const unsigned*)(Ab + ((((unsigned)(idv)) << 7) + qoff)); \
        if (lane < 32) { s0 += ulo(_r); s1 += uhi(_r); } } while (0)

    if (U16) {
        while (j < end && (j & 7)) { ONE1(colu[j]); ++j; }
        int nit = (end - j) >> 3;
        if (nit > 0) {
            uint4 w = *(const uint4*)(colu + j);
            for (int it = 0; it < nit; ++it) {
                unsigned i0 = (w.x >> sh16) & 0xFFFFu;
                unsigned i1 = (w.y >> sh16) & 0xFFFFu;
                unsigned i2 = (w.z >> sh16) & 0xFFFFu;
                unsigned i3 = (w.w >> sh16) & 0xFFFFu;
                unsigned r0 = *(const unsigned*)(Ab + ((i0 << 7) + qoff));
                unsigned r1 = *(const unsigned*)(Ab + ((i1 << 7) + qoff));
                unsigned r2 = *(const unsigned*)(Ab + ((i2 << 7) + qoff));
                unsigned r3 = *(const unsigned*)(Ab + ((i3 << 7) + qoff));
                if (it + 1 < nit) w = *(const uint4*)(colu + j + 8);
                s0 += ulo(r0); s1 += uhi(r0);
                s2 += ulo(r1); s3 += uhi(r1);
                s4 += ulo(r2); s5 += uhi(r2);
                s6 += ulo(r3); s7 += uhi(r3);
                j += 8;
            }
        }
        while (j < end) { ONE1(colu[j]); ++j; }
    } else {
        while (j < end && (j & 7)) { ONE1(coli[j]); ++j; }
        int nit = (end - j) >> 3;
        if (nit > 0) {
            int4 wA = *(const int4*)(coli + j);
            int4 wB = *(const int4*)(coli + j + 4);
            for (int it = 0; it < nit; ++it) {
                unsigned i0 = (unsigned)(half ? wA.y : wA.x);
                unsigned i1 = (unsigned)(half ? wA.w : wA.z);
                unsigned i2 = (unsigned)(half ? wB.y : wB.x);
                unsigned i3 = (unsigned)(half ? wB.w : wB.z);
                unsigned r0 = *(const unsigned*)(Ab + ((i0 << 7) + qoff));
                unsigned r1 = *(const unsigned*)(Ab + ((i1 << 7) + qoff));
                unsigned r2 = *(const unsigned*)(Ab + ((i2 << 7) + qoff));
                unsigned r3 = *(const unsigned*)(Ab + ((i3 << 7) + qoff));
                if (it + 1 < nit) {
                    wA = *(const int4*)(coli + j + 8);
                    wB = *(const int4*)(coli + j + 12);
                }
                s0 += ulo(r0); s1 += uhi(r0);
                s2 += ulo(r1); s3 += uhi(r1);
                s4 += ulo(r2); s5 += uhi(r2);
                s6 += ulo(r3); s7 += uhi(r3);
                j += 8;
            }
        }
        while (j < end) { ONE1(coli[j]); ++j; }
    }
#undef ONE1

    // fold the 8 chains, then combine the two halves
    float a0 = (s0 + s2) + (s4 + s6);
    float a1 = (s1 + s3) + (s5 + s7);
    a0 += __shfl_xor(a0, 32, 64);
    a1 += __shfl_xor(a1, 32, 64);
    if (lane < 32) {
        float inv = 1.0f / fmaxf((float)(end - beg), 1.0f);
        unsigned sv = *(const unsigned*)((const char*)S + ((size_t)node * 128) + qoff);
        float2 c = bf2(sv);
        float v0 = a0 * inv + c.x, v1 = a1 * inv + c.y;
        if (do_relu) { v0 = fmaxf(v0, 0.0f); v1 = fmaxf(v1, 0.0f); }
        *(unsigned*)((char*)out + (size_t)node * 128 + qoff) = pk2(v0, v1);
    }
}

__global__ __launch_bounds__(256) void gather_dual(
    int gm,
    const int2* __restrict__ rp2_m, const int* __restrict__ col_m,
    const unsigned short* __restrict__ AU, const unsigned short* __restrict__ SM,
    unsigned short* __restrict__ outM, int M,
    const int2* __restrict__ rp2_u, const unsigned short* __restrict__ col_u,
    const unsigned short* __restrict__ AM, const unsigned short* __restrict__ SU,
    unsigned short* __restrict__ outU, int U, int do_relu) {
    int b = blockIdx.x;
    if (b < gm) gather_body<0>(b, rp2_m, col_m, (const unsigned short*)0, AU, SM, outM, M, do_relu);
    else gather_body<1>(b - gm, rp2_u, (const int*)0, col_u, AM, SU, outU, U, do_relu);
}

// ---- link head: 8 edges/wave, uint4 lanes ---------------------------------

__global__ __launch_bounds__(256) void dot_bf16(
    const int* __restrict__ ls, const int* __restrict__ ld,
    const unsigned short* __restrict__ xuB, const unsigned short* __restrict__ xmB,
    float* __restrict__ out, int L) {
    int t = blockIdx.x * 256 + threadIdx.x;
    int lane = t & 63;
    int sub = lane >> 3, q = lane & 7;
    int e = (t >> 6) * 8 + sub;
    if (e < L) {
        int u = ls[e], m = ld[e];
        uint4 a = *(const uint4*)(xuB + (size_t)u * 64 + q * 8);
        uint4 b = *(const uint4*)(xmB + (size_t)m * 64 + q * 8);
        float2 a0 = bf2(a.x), a1 = bf2(a.y), a2 = bf2(a.z), a3 = bf2(a.w);
        float2 b0 = bf2(b.x), b1 = bf2(b.y), b2 = bf2(b.z), b3 = bf2(b.w);
        float p = a0.x * b0.x + a0.y * b0.y + a1.x * b1.x + a1.y * b1.y
                + a2.x * b2.x + a2.y * b2.y + a3.x * b3.x + a3.y * b3.y;
#pragma unroll
        for (int off = 1; off < 8; off <<= 1) p += __shfl_xor(p, off, 64);
        if (q == 0) out[e] = p;
    }
}

// ---------------------------------------------------------------------------

extern "C" void kernel_launch(void* const* d_in, const int* in_sizes, int n_in,
                              void* d_out, int out_size, void* d_ws, size_t ws_size,
                              hipStream_t stream) {
    const float* movie_x   = (const float*)d_in[0];
    const float* user_emb  = (const float*)d_in[1];
    const float* movie_emb = (const float*)d_in[2];
    const float* mlw       = (const float*)d_in[3];
    const float* mlb       = (const float*)d_in[4];
    const float* llw       = (const float*)d_in[5];   // [2][2][64][64]
    const float* llb       = (const float*)d_in[6];   // [2][2][64]
    const float* lrw       = (const float*)d_in[7];   // [2][2][64][64]
    const int*   esrc      = (const int*)d_in[8];
    const int*   edst      = (const int*)d_in[9];
    const int*   lsrc      = (const int*)d_in[10];
    const int*   ldst      = (const int*)d_in[11];

    const int U = in_sizes[1] / 64;
    const int M = in_sizes[2] / 64;
    const int E = in_sizes[8];
    const int L = in_sizes[10];
    float* out = (float*)d_out;

    const size_t M64 = (size_t)M * 64, U64 = (size_t)U * 64;
    const int nbu = (U + 255) >> 8;   // 256-user buckets  (391)
    const int nbm = (M + 127) >> 7;   // 128-movie buckets (391)

    // ---- ws layout: 256 B-aligned regions, hot tables first ----
    char* base = (char*)d_ws;
    size_t off = 0;
    auto alloc = [&](size_t bytes) -> void* {
        off = (off + 255) & ~(size_t)255;
        void* p = base + off;
        off += bytes;
        return p;
    };
    unsigned short* bmB0 = (unsigned short*)alloc(M64 * 2);   // movie feat L0 bf16
    unsigned short* buB0 = (unsigned short*)alloc(U64 * 2);   // user feat L0 bf16
    unsigned short* A_m  = (unsigned short*)alloc(M64 * 2);   // bf16, gathered by users
    unsigned short* A_u  = (unsigned short*)alloc(U64 * 2);   // bf16, gathered by movies
    unsigned short* S_m  = (unsigned short*)alloc(M64 * 2);   // bf16 self term
    unsigned short* S_u  = (unsigned short*)alloc(U64 * 2);
    unsigned short* xm1  = (unsigned short*)alloc(M64 * 2);   // layer-0 movie out
    unsigned short* xu1  = (unsigned short*)alloc(U64 * 2);   // layer-0 user out
    float* wTl = (float*)alloc(4 * 4096 * 4);
    float* wTr = (float*)alloc(4 * 4096 * 4);
    int2* rp2_m = (int2*)alloc((size_t)M * 8);
    int2* rp2_u = (int2*)alloc((size_t)U * 8);
    int* col_m = (int*)alloc((size_t)nbm * BC * 4);           // padded, user ids
    unsigned short* col_u = (unsigned short*)alloc((size_t)nbu * BC * 2);
    int* bfu = (int*)alloc(800 * 4);                          // ONE region: bfu|bfm
    int* bfm = bfu + 400;
    int* part_u = (int*)alloc((size_t)nbu * BC * 4);          // packed 24-bit
    int* part_m = (int*)alloc((size_t)nbm * BC * 4);
    // final tables alias the (dead-by-then) part buffers (contiguous, aligned):
    unsigned short* xm2 = (unsigned short*)part_u;            // [M,64] final movie
    unsigned short* xu2 = xm2 + M64;                          // [U,64] final user

    const int np    = (E + CHP - 1) / CHP;                    // dual-dir chunks
    const int cvtb  = (U * 16 / 4 + 255) / 256;               // 4 float4/thread
    const int ntm = (M + 127) / 128, ntu = (U + 127) / 128;   // 128-node tiles
    const int gm_g = (M * 64 + 255) / 256, gu_g = (U * 64 + 255) / 256;

    // ---- build_a: dual-dir register partition + prep (fused) ----
    hipMemsetAsync(bfu, 0, 800 * sizeof(int), stream);
    build_a<<<np + 1088 + cvtb, 256, 0, stream>>>(
        np, esrc, edst, E, nbu, nbm, bfu, bfm, part_u, part_m,
        movie_x, mlw, mlb, movie_emb, bmB0, M,
        llw, lrw, wTl, wTr, user_emb, buB0, U * 16);

    // ---- build_b: fine CSR + transform L0 (fused) ----
    build_b<<<nbm + nbu + TBM + TBU, 256, 0, stream>>>(
        nbm, nbu, ntm, ntu,
        part_m, bfm, rp2_m, col_m, M,
        part_u, bfu, rp2_u, col_u, U,
        bmB0, wTl + 1 * 4096, wTr + 0 * 4096, llb + 0 * 64, A_m, S_m,
        buB0, wTl + 0 * 4096, wTr + 1 * 4096, llb + 1 * 64, A_u, S_u);

    // ---- layer 0 gather ----
    gather_dual<<<gm_g + gu_g, 256, 0, stream>>>(gm_g,
        rp2_m, col_m, A_u, S_m, xm1, M,
        rp2_u, col_u, A_m, S_u, xu1, U, 1);

    // ---- layer 1 ---- (A/S reused; part buffers now dead -> xm2/xu2)
    transform_dual<<<TBM + TBU, 256, 0, stream>>>(ntm, ntu,
        xm1, wTl + 3 * 4096, wTr + 2 * 4096, llb + 2 * 64, A_m, S_m, M,
        xu1, wTl + 2 * 4096, wTr + 3 * 4096, llb + 3 * 64, A_u, S_u, U);
    gather_dual<<<gm_g + gu_g, 256, 0, stream>>>(gm_g,
        rp2_m, col_m, A_u, S_m, xm2, M,
        rp2_u, col_u, A_m, S_u, xu2, U, 0);

    // ---- link head ----
    dot_bf16<<<(L + 31) / 32, 256, 0, stream>>>(lsrc, ldst, xu2, xm2, out, L);
}

// Round 8
// 378.564 us; speedup vs baseline: 1.4153x; 1.4153x over previous
//
#include <hip/hip_runtime.h>

// ---------------------------------------------------------------------------
// Round 27: gather REVERTED to R19 (measured 82.7us, best known; R21-R26
// restructures all latency-bound regressions). One new diff: MFMA transform.
//  - transform rewritten with mfma_f32_16x16x32_bf16: no LDS, W bf16 frags
//    preloaded in registers (16 x bf16x8), X frags loaded direct from global,
//    C/D layout col=lane&15 row=(lane>>4)*4+reg (m89-verified).
//  - build_a now emits bf16 W tables (wTlB/wTrB) instead of f32.
//  - build_b LDS 50KB -> 2KB (fine CSR only).
// absmax may rise slightly (W now bf16; accum still f32).
// ---------------------------------------------------------------------------

#define CHP 4096  // edges per partition block (both directions)
#define BC 6144   // bucket capacity (E[cnt]=5120, sigma=72 -> 14-sigma margin)

typedef __attribute__((ext_vector_type(8))) short bf16x8;
typedef __attribute__((ext_vector_type(4))) float f32x4;

__device__ __forceinline__ float b2f(unsigned short u) {
    union { unsigned int i; float f; } v; v.i = ((unsigned int)u) << 16; return v.f;
}
__device__ __forceinline__ unsigned short f2b(float f) {
    union { float f; unsigned int i; } v; v.f = f;
    unsigned int i = v.i;
    return (unsigned short)((i + 0x7FFFu + ((i >> 16) & 1u)) >> 16);  // RNE
}
__device__ __forceinline__ float2 bf2(unsigned int w) {   // unpack 2 bf16
    union { unsigned int i; float f; } lo, hi;
    lo.i = w << 16; hi.i = w & 0xFFFF0000u;
    return make_float2(lo.f, hi.f);
}
__device__ __forceinline__ unsigned int pk2(float a, float b) {
    return (unsigned int)f2b(a) | ((unsigned int)f2b(b) << 16);
}

// ---- build_a: [0,np) dual-dir partition | movie_init | wt(bf16) | cvt -----

__global__ __launch_bounds__(256) void build_a(
    int np,
    const int* __restrict__ src, const int* __restrict__ dst, int E,
    int nbu, int nbm, int* __restrict__ bfu, int* __restrict__ bfm,
    int* __restrict__ pu, int* __restrict__ pm,
    const float* __restrict__ movie_x, const float* __restrict__ wm,
    const float* __restrict__ bm, const float* __restrict__ memb,
    unsigned short* __restrict__ xmB, int M,
    const float* __restrict__ llw, const float* __restrict__ lrw,
    unsigned short* __restrict__ wTlB, unsigned short* __restrict__ wTrB,
    const float* __restrict__ uemb, unsigned short* __restrict__ buB, int n4u) {
    __shared__ int2 stag[CHP];           // 32 KB ordered staging (per direction)
    __shared__ int hist[512];
    __shared__ int scn[512];
    __shared__ int gb[400];
    __shared__ int lst[400];
    int t = threadIdx.x;
    int b = blockIdx.x;
    if (b < np) {
        // ---- one chunk, both directions; edges held in registers ----
        int c0 = b * CHP, lim = min(c0 + CHP, E), cnt = lim - c0;
        int ks[16], vs[16];
#pragma unroll
        for (int i = 0; i < 16; ++i) {
            int e = c0 + t + i * 256;
            if (e < lim) { ks[i] = src[e]; vs[i] = dst[e]; }
            else { ks[i] = 0; vs[i] = 0; }
        }
        for (int dir = 0; dir < 2; ++dir) {
            const int NB = dir ? nbm : nbu;
            const int SHIFT = dir ? 7 : 8;
            int* bf = dir ? bfm : bfu;
            int* P  = dir ? pm  : pu;
            __syncthreads();   // protect stag/hist reuse from previous dir
            for (int i = t; i < 512; i += 256) hist[i] = 0;
            __syncthreads();
#pragma unroll
            for (int i = 0; i < 16; ++i) {
                if (t + i * 256 < cnt) {
                    int k = dir ? vs[i] : ks[i];
                    atomicAdd(&hist[k >> SHIFT], 1);
                }
            }
            __syncthreads();
            scn[t] = hist[t]; scn[t + 256] = hist[t + 256];
            __syncthreads();
            for (int off = 1; off < 512; off <<= 1) {
                int v0 = scn[t],  a0 = (t >= off) ? scn[t - off] : 0;
                int i1 = t + 256;
                int v1 = scn[i1], a1 = scn[i1 - off];
                __syncthreads();
                scn[t] = v0 + a0; scn[i1] = v1 + a1;
                __syncthreads();
            }
            for (int i = t; i < NB; i += 256) {
                int c = hist[i];
                lst[i] = scn[i] - c;
                int r = c ? atomicAdd(&bf[i], c) : 0;
                if (r < 0) r = 0;
                if (r + c > BC) r = BC - c;
                gb[i] = i * BC + r;
            }
            __syncthreads();
            for (int i = t; i < 512; i += 256) hist[i] = (i < NB) ? lst[i] : 0;
            __syncthreads();
#pragma unroll
            for (int i = 0; i < 16; ++i) {
                if (t + i * 256 < cnt) {
                    int k = dir ? vs[i] : ks[i];
                    int v = dir ? ks[i] : vs[i];
                    int bk = k >> SHIFT;
                    int pos = atomicAdd(&hist[bk], 1);
                    int packed = dir ? ((v << 7) | (k & 127)) : ((v << 8) | (k & 255));
                    stag[pos] = make_int2(packed, bk);
                }
            }
            __syncthreads();
            for (int j = t; j < cnt; j += 256) {
                int2 s = stag[j];
                P[gb[s.y] + (j - lst[s.y])] = s.x;
            }
        }
        return;
    }
    int lb = b - np;
    if (lb < 1024) {
        float* w_s = (float*)stag;   // 64*21 floats
        for (int i = t; i < 64 * 20; i += 256) {
            int h = i / 20, f = i % 20;
            w_s[h * 21 + f] = wm[i];
        }
        __syncthreads();
        int lane = t & 63;
        float bias = bm[lane];
        int nw = (1024 * 256) >> 6;
        int w  = (lb * 256 + t) >> 6;
        for (int m = w; m < M; m += nw) {
            float fv  = (lane < 20) ? movie_x[m * 20 + lane] : 0.0f;
            float acc = bias + memb[m * 64 + lane];
#pragma unroll
            for (int f = 0; f < 20; ++f) {
                float xv = __shfl(fv, f, 64);
                acc += xv * w_s[lane * 21 + f];
            }
            xmB[m * 64 + lane] = f2b(acc);
        }
    } else if (lb < 1088) {
        int i = (lb - 1024) * 256 + t;
        int s = i >> 12, rem = i & 4095, k = rem >> 6, h = rem & 63;
        wTlB[i] = f2b(llw[s * 4096 + h * 64 + k]);
        wTrB[i] = f2b(lrw[s * 4096 + h * 64 + k]);
    } else {
        int i0 = ((lb - 1088) * 256 + t) * 4;
#pragma unroll
        for (int k = 0; k < 4; ++k) {
            int i = i0 + k;
            if (i < n4u) {
                float4 v = ((const float4*)uemb)[i];
                ushort4 o;
                o.x = f2b(v.x); o.y = f2b(v.y); o.z = f2b(v.z); o.w = f2b(v.w);
                ((ushort4*)buB)[i] = o;
            }
        }
    }
}

// ---- MFMA transform: 128-node tiles, no LDS -------------------------------
// Wave w owns rows [tile*128 + w*32, +32). W (bf16, [64k][64h]) preloaded as
// 16 bf16x8 fragments per (A,S). X frags loaded direct from global (16B/lane).
// mfma_f32_16x16x32_bf16; C/D: col = lane&15, row = (lane>>4)*4 + reg (m89).

__device__ __forceinline__ void transform_tiles_mfma(
    int tile0, int stride, int ntiles,
    const unsigned short* __restrict__ X,
    const unsigned short* __restrict__ wA,   // bf16 [64][64] k-major
    const unsigned short* __restrict__ wS,
    const float* __restrict__ bS,
    unsigned short* __restrict__ A, unsigned short* __restrict__ S, int n) {
    int tid = threadIdx.x;
    int wave = tid >> 6, lane = tid & 63;
    int lrow = lane & 15;        // A row / B col / D col within 16
    int lkb  = lane >> 4;        // k-block (8 k each) / D row-block

    // ---- preload W fragments: [col-tile][k-step] ----
    bf16x8 fa[4][2], fs[4][2];
#pragma unroll
    for (int ct = 0; ct < 4; ++ct)
#pragma unroll
        for (int ksp = 0; ksp < 2; ++ksp) {
            int col = ct * 16 + lrow;
            int k0  = ksp * 32 + lkb * 8;
#pragma unroll
            for (int j = 0; j < 8; ++j) {
                fa[ct][ksp][j] = (short)wA[(k0 + j) * 64 + col];
                fs[ct][ksp][j] = (short)wS[(k0 + j) * 64 + col];
            }
        }
    float bias[4];
#pragma unroll
    for (int ct = 0; ct < 4; ++ct) bias[ct] = bS[ct * 16 + lrow];
    const bf16x8 zf = {0, 0, 0, 0, 0, 0, 0, 0};

    for (int tile = tile0; tile < ntiles; tile += stride) {
        int node0 = tile * 128 + wave * 32;
        bf16x8 xa[2][2];
#pragma unroll
        for (int rt = 0; rt < 2; ++rt) {
            int node = node0 + rt * 16 + lrow;
#pragma unroll
            for (int ksp = 0; ksp < 2; ++ksp) {
                xa[rt][ksp] = (node < n)
                    ? *(const bf16x8*)(X + (size_t)node * 64 + ksp * 32 + lkb * 8)
                    : zf;
            }
        }
#pragma unroll
        for (int rt = 0; rt < 2; ++rt) {
#pragma unroll
            for (int ct = 0; ct < 4; ++ct) {
                f32x4 accA = {0.f, 0.f, 0.f, 0.f}, accS = {0.f, 0.f, 0.f, 0.f};
                accA = __builtin_amdgcn_mfma_f32_16x16x32_bf16(xa[rt][0], fa[ct][0], accA, 0, 0, 0);
                accA = __builtin_amdgcn_mfma_f32_16x16x32_bf16(xa[rt][1], fa[ct][1], accA, 0, 0, 0);
                accS = __builtin_amdgcn_mfma_f32_16x16x32_bf16(xa[rt][0], fs[ct][0], accS, 0, 0, 0);
                accS = __builtin_amdgcn_mfma_f32_16x16x32_bf16(xa[rt][1], fs[ct][1], accS, 0, 0, 0);
#pragma unroll
                for (int r = 0; r < 4; ++r) {
                    int row = node0 + rt * 16 + lkb * 4 + r;
                    if (row < n) {
                        A[(size_t)row * 64 + ct * 16 + lrow] = f2b(accA[r]);
                        S[(size_t)row * 64 + ct * 16 + lrow] = f2b(accS[r] + bias[ct]);
                    }
                }
            }
        }
    }
}

// ---- fine CSR body --------------------------------------------------------

template <int NPB, int SH, typename CT>
__device__ __forceinline__ void fine_body(
    int b, int* c, int* sc, const int* __restrict__ part,
    const int* __restrict__ cnt_arr,
    int2* __restrict__ rp2, CT* __restrict__ col, int n) {
    int cnt = min(cnt_arr[b], BC);
    int pb = b * BC;
    int t = threadIdx.x;
    c[t] = 0;
    __syncthreads();
    const int mask = NPB - 1;
    for (int j = t; j < cnt; j += 256)
        atomicAdd(&c[part[pb + j] & mask], 1);
    __syncthreads();
    int own = c[t];
    sc[t] = own;
    __syncthreads();
    for (int off = 1; off < 256; off <<= 1) {
        int val = sc[t];
        int add = (t >= off) ? sc[t - off] : 0;
        __syncthreads();
        sc[t] = val + add;
        __syncthreads();
    }
    int start = pb + sc[t] - own;
    int node = b * NPB + t;
    if (t < NPB && node < n) rp2[node] = make_int2(start, start + own);
    __syncthreads();
    c[t] = start;
    __syncthreads();
    for (int j = t; j < cnt; j += 256) {
        int p = part[pb + j];
        int off = atomicAdd(&c[p & mask], 1);
        col[off] = (CT)(((unsigned)p) >> SH);
    }
}

#define TBM 256   // movie transform blocks
#define TBU 512   // user transform blocks

// ---- build_b: [0, nbm+nbu) fine CSR | +TBM movie transform | +TBU user ----

__global__ __launch_bounds__(256) void build_b(
    int nbm, int nbu, int ntm, int ntu,
    const int* __restrict__ pm, const int* __restrict__ cm,
    int2* __restrict__ rp2_m, int* __restrict__ col_m, int M,
    const int* __restrict__ pu, const int* __restrict__ cu,
    int2* __restrict__ rp2_u, unsigned short* __restrict__ col_u, int U,
    const unsigned short* __restrict__ xM, const unsigned short* __restrict__ wAM,
    const unsigned short* __restrict__ wSM, const float* __restrict__ bSM,
    unsigned short* __restrict__ AM, unsigned short* __restrict__ SM,
    const unsigned short* __restrict__ xU, const unsigned short* __restrict__ wAU,
    const unsigned short* __restrict__ wSU, const float* __restrict__ bSU,
    unsigned short* __restrict__ AU, unsigned short* __restrict__ SU) {
    __shared__ int cs[512];   // fine CSR counters + scan only (2 KB)
    int b = blockIdx.x;
    if (b < nbm) {
        fine_body<128, 7, int>(b, cs, cs + 256, pm, cm, rp2_m, col_m, M);
        return;
    }
    b -= nbm;
    if (b < nbu) {
        fine_body<256, 8, unsigned short>(b, cs, cs + 256, pu, cu, rp2_u, col_u, U);
        return;
    }
    b -= nbu;
    if (b < TBM) transform_tiles_mfma(b, TBM, ntm, xM, wAM, wSM, bSM, AM, SM, M);
    else transform_tiles_mfma(b - TBM, TBU, ntu, xU, wAU, wSU, bSU, AU, SU, U);
}

// ---- standalone transform (layer 1) ---------------------------------------

__global__ __launch_bounds__(256) void transform_dual(
    int ntm, int ntu,
    const unsigned short* __restrict__ xM, const unsigned short* __restrict__ wAM,
    const unsigned short* __restrict__ wSM, const float* __restrict__ bSM,
    unsigned short* __restrict__ AM, unsigned short* __restrict__ SM, int M,
    const unsigned short* __restrict__ xU, const unsigned short* __restrict__ wAU,
    const unsigned short* __restrict__ wSU, const float* __restrict__ bSU,
    unsigned short* __restrict__ AU, unsigned short* __restrict__ SU, int U) {
    int b = blockIdx.x;
    if (b < TBM) transform_tiles_mfma(b, TBM, ntm, xM, wAM, wSM, bSM, AM, SM, M);
    else transform_tiles_mfma(b - TBM, TBU, ntu, xU, wAU, wSU, bSU, AU, SU, U);
}

// ---- dual gather: 8 groups x 8 lanes, uint4 rows (R19 verbatim) -----------

template <typename CT>
__device__ __forceinline__ void gather_body(
    int b, const int2* __restrict__ rp2, const CT* __restrict__ col,
    const unsigned short* __restrict__ A, const unsigned short* __restrict__ S,
    unsigned short* __restrict__ out, int n, int do_relu) {
    int node = (b * 256 + threadIdx.x) >> 6;
    if (node >= n) return;
    int lane = threadIdx.x & 63;
    int g = lane >> 3, q = lane & 7;     // 8 neighbor-groups x 8 feature-lanes
    int2 be = rp2[node];
    int beg = be.x, end = be.y;
    float s0 = 0, s1 = 0, s2 = 0, s3 = 0, s4 = 0, s5 = 0, s6 = 0, s7 = 0;
    float t0 = 0, t1 = 0, t2 = 0, t3 = 0, t4 = 0, t5 = 0, t6 = 0, t7 = 0;
    int j = beg + g;
    for (; j + 8 < end; j += 16) {
        int n0 = (int)col[j], n1 = (int)col[j + 8];
        uint4 w0 = *(const uint4*)(A + (size_t)n0 * 64 + q * 8);
        uint4 w1 = *(const uint4*)(A + (size_t)n1 * 64 + q * 8);
        float2 p;
        p = bf2(w0.x); s0 += p.x; s1 += p.y;
        p = bf2(w0.y); s2 += p.x; s3 += p.y;
        p = bf2(w0.z); s4 += p.x; s5 += p.y;
        p = bf2(w0.w); s6 += p.x; s7 += p.y;
        p = bf2(w1.x); t0 += p.x; t1 += p.y;
        p = bf2(w1.y); t2 += p.x; t3 += p.y;
        p = bf2(w1.z); t4 += p.x; t5 += p.y;
        p = bf2(w1.w); t6 += p.x; t7 += p.y;
    }
    if (j < end) {
        int n0 = (int)col[j];
        uint4 w0 = *(const uint4*)(A + (size_t)n0 * 64 + q * 8);
        float2 p;
        p = bf2(w0.x); s0 += p.x; s1 += p.y;
        p = bf2(w0.y); s2 += p.x; s3 += p.y;
        p = bf2(w0.z); s4 += p.x; s5 += p.y;
        p = bf2(w0.w); s6 += p.x; s7 += p.y;
    }
    s0 += t0; s1 += t1; s2 += t2; s3 += t3;
    s4 += t4; s5 += t5; s6 += t6; s7 += t7;
#pragma unroll
    for (int off = 8; off < 64; off <<= 1) {
        s0 += __shfl_xor(s0, off, 64); s1 += __shfl_xor(s1, off, 64);
        s2 += __shfl_xor(s2, off, 64); s3 += __shfl_xor(s3, off, 64);
        s4 += __shfl_xor(s4, off, 64); s5 += __shfl_xor(s5, off, 64);
        s6 += __shfl_xor(s6, off, 64); s7 += __shfl_xor(s7, off, 64);
    }
    if (g == 0) {
        float inv = 1.0f / fmaxf((float)(end - beg), 1.0f);
        uint4 sv = *(const uint4*)(S + (size_t)node * 64 + q * 8);
        float2 c0 = bf2(sv.x), c1 = bf2(sv.y), c2 = bf2(sv.z), c3 = bf2(sv.w);
        float v0 = s0 * inv + c0.x, v1 = s1 * inv + c0.y;
        float v2 = s2 * inv + c1.x, v3 = s3 * inv + c1.y;
        float v4 = s4 * inv + c2.x, v5 = s5 * inv + c2.y;
        float v6 = s6 * inv + c3.x, v7 = s7 * inv + c3.y;
        if (do_relu) {
            v0 = fmaxf(v0, 0.f); v1 = fmaxf(v1, 0.f); v2 = fmaxf(v2, 0.f);
            v3 = fmaxf(v3, 0.f); v4 = fmaxf(v4, 0.f); v5 = fmaxf(v5, 0.f);
            v6 = fmaxf(v6, 0.f); v7 = fmaxf(v7, 0.f);
        }
        uint4 o;
        o.x = pk2(v0, v1); o.y = pk2(v2, v3); o.z = pk2(v4, v5); o.w = pk2(v6, v7);
        *(uint4*)(out + (size_t)node * 64 + q * 8) = o;
    }
}

__global__ __launch_bounds__(256) void gather_dual(
    int gm,
    const int2* __restrict__ rp2_m, const int* __restrict__ col_m,
    const unsigned short* __restrict__ AU, const unsigned short* __restrict__ SM,
    unsigned short* __restrict__ outM, int M,
    const int2* __restrict__ rp2_u, const unsigned short* __restrict__ col_u,
    const unsigned short* __restrict__ AM, const unsigned short* __restrict__ SU,
    unsigned short* __restrict__ outU, int U, int do_relu) {
    int b = blockIdx.x;
    if (b < gm) gather_body<int>(b, rp2_m, col_m, AU, SM, outM, M, do_relu);
    else gather_body<unsigned short>(b - gm, rp2_u, col_u, AM, SU, outU, U, do_relu);
}

// ---- link head: 8 edges/wave, uint4 lanes ---------------------------------

__global__ __launch_bounds__(256) void dot_bf16(
    const int* __restrict__ ls, const int* __restrict__ ld,
    const unsigned short* __restrict__ xuB, const unsigned short* __restrict__ xmB,
    float* __restrict__ out, int L) {
    int t = blockIdx.x * 256 + threadIdx.x;
    int lane = t & 63;
    int sub = lane >> 3, q = lane & 7;
    int e = (t >> 6) * 8 + sub;
    if (e < L) {
        int u = ls[e], m = ld[e];
        uint4 a = *(const uint4*)(xuB + (size_t)u * 64 + q * 8);
        uint4 b = *(const uint4*)(xmB + (size_t)m * 64 + q * 8);
        float2 a0 = bf2(a.x), a1 = bf2(a.y), a2 = bf2(a.z), a3 = bf2(a.w);
        float2 b0 = bf2(b.x), b1 = bf2(b.y), b2 = bf2(b.z), b3 = bf2(b.w);
        float p = a0.x * b0.x + a0.y * b0.y + a1.x * b1.x + a1.y * b1.y
                + a2.x * b2.x + a2.y * b2.y + a3.x * b3.x + a3.y * b3.y;
#pragma unroll
        for (int off = 1; off < 8; off <<= 1) p += __shfl_xor(p, off, 64);
        if (q == 0) out[e] = p;
    }
}

// ---------------------------------------------------------------------------

extern "C" void kernel_launch(void* const* d_in, const int* in_sizes, int n_in,
                              void* d_out, int out_size, void* d_ws, size_t ws_size,
                              hipStream_t stream) {
    const float* movie_x   = (const float*)d_in[0];
    const float* user_emb  = (const float*)d_in[1];
    const float* movie_emb = (const float*)d_in[2];
    const float* mlw       = (const float*)d_in[3];
    const float* mlb       = (const float*)d_in[4];
    const float* llw       = (const float*)d_in[5];   // [2][2][64][64]
    const float* llb       = (const float*)d_in[6];   // [2][2][64]
    const float* lrw       = (const float*)d_in[7];   // [2][2][64][64]
    const int*   esrc      = (const int*)d_in[8];
    const int*   edst      = (const int*)d_in[9];
    const int*   lsrc      = (const int*)d_in[10];
    const int*   ldst      = (const int*)d_in[11];

    const int U = in_sizes[1] / 64;
    const int M = in_sizes[2] / 64;
    const int E = in_sizes[8];
    const int L = in_sizes[10];
    float* out = (float*)d_out;

    const size_t M64 = (size_t)M * 64, U64 = (size_t)U * 64;
    const int nbu = (U + 255) >> 8;   // 256-user buckets  (391)
    const int nbm = (M + 127) >> 7;   // 128-movie buckets (391)

    // ---- ws layout: 256 B-aligned regions, hot tables first ----
    char* base = (char*)d_ws;
    size_t off = 0;
    auto alloc = [&](size_t bytes) -> void* {
        off = (off + 255) & ~(size_t)255;
        void* p = base + off;
        off += bytes;
        return p;
    };
    unsigned short* bmB0 = (unsigned short*)alloc(M64 * 2);   // movie feat L0 bf16
    unsigned short* buB0 = (unsigned short*)alloc(U64 * 2);   // user feat L0 bf16
    unsigned short* A_m  = (unsigned short*)alloc(M64 * 2);   // bf16, gathered by users
    unsigned short* A_u  = (unsigned short*)alloc(U64 * 2);   // bf16, gathered by movies
    unsigned short* S_m  = (unsigned short*)alloc(M64 * 2);   // bf16 self term
    unsigned short* S_u  = (unsigned short*)alloc(U64 * 2);
    unsigned short* xm1  = (unsigned short*)alloc(M64 * 2);   // layer-0 movie out
    unsigned short* xu1  = (unsigned short*)alloc(U64 * 2);   // layer-0 user out
    unsigned short* wTlB = (unsigned short*)alloc(4 * 4096 * 2);  // bf16 W tables
    unsigned short* wTrB = (unsigned short*)alloc(4 * 4096 * 2);
    int2* rp2_m = (int2*)alloc((size_t)M * 8);
    int2* rp2_u = (int2*)alloc((size_t)U * 8);
    int* col_m = (int*)alloc((size_t)nbm * BC * 4);           // padded, user ids
    unsigned short* col_u = (unsigned short*)alloc((size_t)nbu * BC * 2);
    int* bfu = (int*)alloc(800 * 4);                          // ONE region: bfu|bfm
    int* bfm = bfu + 400;
    int* part_u = (int*)alloc((size_t)nbu * BC * 4);          // packed 24-bit
    int* part_m = (int*)alloc((size_t)nbm * BC * 4);
    // final tables alias the (dead-by-then) part buffers (contiguous, aligned):
    unsigned short* xm2 = (unsigned short*)part_u;            // [M,64] final movie
    unsigned short* xu2 = xm2 + M64;                          // [U,64] final user

    const int np    = (E + CHP - 1) / CHP;                    // dual-dir chunks
    const int cvtb  = (U * 16 / 4 + 255) / 256;               // 4 float4/thread
    const int ntm = (M + 127) / 128, ntu = (U + 127) / 128;   // 128-node tiles
    const int gm_g = (M * 64 + 255) / 256, gu_g = (U * 64 + 255) / 256;

    // ---- build_a: dual-dir register partition + prep (fused) ----
    hipMemsetAsync(bfu, 0, 800 * sizeof(int), stream);
    build_a<<<np + 1088 + cvtb, 256, 0, stream>>>(
        np, esrc, edst, E, nbu, nbm, bfu, bfm, part_u, part_m,
        movie_x, mlw, mlb, movie_emb, bmB0, M,
        llw, lrw, wTlB, wTrB, user_emb, buB0, U * 16);

    // ---- build_b: fine CSR + transform L0 (fused, MFMA) ----
    build_b<<<nbm + nbu + TBM + TBU, 256, 0, stream>>>(
        nbm, nbu, ntm, ntu,
        part_m, bfm, rp2_m, col_m, M,
        part_u, bfu, rp2_u, col_u, U,
        bmB0, wTlB + 1 * 4096, wTrB + 0 * 4096, llb + 0 * 64, A_m, S_m,
        buB0, wTlB + 0 * 4096, wTrB + 1 * 4096, llb + 1 * 64, A_u, S_u);

    // ---- layer 0 gather ----
    gather_dual<<<gm_g + gu_g, 256, 0, stream>>>(gm_g,
        rp2_m, col_m, A_u, S_m, xm1, M,
        rp2_u, col_u, A_m, S_u, xu1, U, 1);

    // ---- layer 1 ---- (A/S reused; part buffers now dead -> xm2/xu2)
    transform_dual<<<TBM + TBU, 256, 0, stream>>>(ntm, ntu,
        xm1, wTlB + 3 * 4096, wTrB + 2 * 4096, llb + 2 * 64, A_m, S_m, M,
        xu1, wTlB + 2 * 4096, wTrB + 3 * 4096, llb + 3 * 64, A_u, S_u, U);
    gather_dual<<<gm_g + gu_g, 256, 0, stream>>>(gm_g,
        rp2_m, col_m, A_u, S_m, xm2, M,
        rp2_u, col_u, A_m, S_u, xu2, U, 0);

    // ---- link head ----
    dot_bf16<<<(L + 31) / 32, 256, 0, stream>>>(lsrc, ldst, xu2, xm2, out, L);
}

// Round 10
// 354.220 us; speedup vs baseline: 1.5125x; 1.0687x over previous
//
#include <hip/hip_runtime.h>

// ---------------------------------------------------------------------------
// Round 29: resubmit of R28 (bench infra timeout — never measured).
// Group-per-node gather (8 nodes/wave, zero-shuffle epilogue).
//  R27 kept: MFMA transform (mfma_f32_16x16x32_bf16, no LDS), bf16 W tables,
//  2KB-LDS build_b. Single diff under test: gather_dual restructured so each
//  8-lane group owns a WHOLE node: same R19 main loop (2 uint4 row loads in
//  flight, 16 independent chains) but no 24-shfl epilogue; lane q holds
//  features q*8..q*8+7 of its node and stores them directly. Cost: degree
//  divergence within the 8 nodes of a wave (max/mean ~1.35); saving: ~90
//  instrs/node.
// ---------------------------------------------------------------------------

#define CHP 4096  // edges per partition block (both directions)
#define BC 6144   // bucket capacity (E[cnt]=5120, sigma=72 -> 14-sigma margin)

typedef __attribute__((ext_vector_type(8))) short bf16x8;
typedef __attribute__((ext_vector_type(4))) float f32x4;

__device__ __forceinline__ float b2f(unsigned short u) {
    union { unsigned int i; float f; } v; v.i = ((unsigned int)u) << 16; return v.f;
}
__device__ __forceinline__ unsigned short f2b(float f) {
    union { float f; unsigned int i; } v; v.f = f;
    unsigned int i = v.i;
    return (unsigned short)((i + 0x7FFFu + ((i >> 16) & 1u)) >> 16);  // RNE
}
__device__ __forceinline__ float2 bf2(unsigned int w) {   // unpack 2 bf16
    union { unsigned int i; float f; } lo, hi;
    lo.i = w << 16; hi.i = w & 0xFFFF0000u;
    return make_float2(lo.f, hi.f);
}
__device__ __forceinline__ unsigned int pk2(float a, float b) {
    return (unsigned int)f2b(a) | ((unsigned int)f2b(b) << 16);
}

// ---- build_a: [0,np) dual-dir partition | movie_init | wt(bf16) | cvt -----

__global__ __launch_bounds__(256) void build_a(
    int np,
    const int* __restrict__ src, const int* __restrict__ dst, int E,
    int nbu, int nbm, int* __restrict__ bfu, int* __restrict__ bfm,
    int* __restrict__ pu, int* __restrict__ pm,
    const float* __restrict__ movie_x, const float* __restrict__ wm,
    const float* __restrict__ bm, const float* __restrict__ memb,
    unsigned short* __restrict__ xmB, int M,
    const float* __restrict__ llw, const float* __restrict__ lrw,
    unsigned short* __restrict__ wTlB, unsigned short* __restrict__ wTrB,
    const float* __restrict__ uemb, unsigned short* __restrict__ buB, int n4u) {
    __shared__ int2 stag[CHP];           // 32 KB ordered staging (per direction)
    __shared__ int hist[512];
    __shared__ int scn[512];
    __shared__ int gb[400];
    __shared__ int lst[400];
    int t = threadIdx.x;
    int b = blockIdx.x;
    if (b < np) {
        // ---- one chunk, both directions; edges held in registers ----
        int c0 = b * CHP, lim = min(c0 + CHP, E), cnt = lim - c0;
        int ks[16], vs[16];
#pragma unroll
        for (int i = 0; i < 16; ++i) {
            int e = c0 + t + i * 256;
            if (e < lim) { ks[i] = src[e]; vs[i] = dst[e]; }
            else { ks[i] = 0; vs[i] = 0; }
        }
        for (int dir = 0; dir < 2; ++dir) {
            const int NB = dir ? nbm : nbu;
            const int SHIFT = dir ? 7 : 8;
            int* bf = dir ? bfm : bfu;
            int* P  = dir ? pm  : pu;
            __syncthreads();   // protect stag/hist reuse from previous dir
            for (int i = t; i < 512; i += 256) hist[i] = 0;
            __syncthreads();
#pragma unroll
            for (int i = 0; i < 16; ++i) {
                if (t + i * 256 < cnt) {
                    int k = dir ? vs[i] : ks[i];
                    atomicAdd(&hist[k >> SHIFT], 1);
                }
            }
            __syncthreads();
            scn[t] = hist[t]; scn[t + 256] = hist[t + 256];
            __syncthreads();
            for (int off = 1; off < 512; off <<= 1) {
                int v0 = scn[t],  a0 = (t >= off) ? scn[t - off] : 0;
                int i1 = t + 256;
                int v1 = scn[i1], a1 = scn[i1 - off];
                __syncthreads();
                scn[t] = v0 + a0; scn[i1] = v1 + a1;
                __syncthreads();
            }
            for (int i = t; i < NB; i += 256) {
                int c = hist[i];
                lst[i] = scn[i] - c;
                int r = c ? atomicAdd(&bf[i], c) : 0;
                if (r < 0) r = 0;
                if (r + c > BC) r = BC - c;
                gb[i] = i * BC + r;
            }
            __syncthreads();
            for (int i = t; i < 512; i += 256) hist[i] = (i < NB) ? lst[i] : 0;
            __syncthreads();
#pragma unroll
            for (int i = 0; i < 16; ++i) {
                if (t + i * 256 < cnt) {
                    int k = dir ? vs[i] : ks[i];
                    int v = dir ? ks[i] : vs[i];
                    int bk = k >> SHIFT;
                    int pos = atomicAdd(&hist[bk], 1);
                    int packed = dir ? ((v << 7) | (k & 127)) : ((v << 8) | (k & 255));
                    stag[pos] = make_int2(packed, bk);
                }
            }
            __syncthreads();
            for (int j = t; j < cnt; j += 256) {
                int2 s = stag[j];
                P[gb[s.y] + (j - lst[s.y])] = s.x;
            }
        }
        return;
    }
    int lb = b - np;
    if (lb < 1024) {
        float* w_s = (float*)stag;   // 64*21 floats
        for (int i = t; i < 64 * 20; i += 256) {
            int h = i / 20, f = i % 20;
            w_s[h * 21 + f] = wm[i];
        }
        __syncthreads();
        int lane = t & 63;
        float bias = bm[lane];
        int nw = (1024 * 256) >> 6;
        int w  = (lb * 256 + t) >> 6;
        for (int m = w; m < M; m += nw) {
            float fv  = (lane < 20) ? movie_x[m * 20 + lane] : 0.0f;
            float acc = bias + memb[m * 64 + lane];
#pragma unroll
            for (int f = 0; f < 20; ++f) {
                float xv = __shfl(fv, f, 64);
                acc += xv * w_s[lane * 21 + f];
            }
            xmB[m * 64 + lane] = f2b(acc);
        }
    } else if (lb < 1088) {
        int i = (lb - 1024) * 256 + t;
        int s = i >> 12, rem = i & 4095, k = rem >> 6, h = rem & 63;
        wTlB[i] = f2b(llw[s * 4096 + h * 64 + k]);
        wTrB[i] = f2b(lrw[s * 4096 + h * 64 + k]);
    } else {
        int i0 = ((lb - 1088) * 256 + t) * 4;
#pragma unroll
        for (int k = 0; k < 4; ++k) {
            int i = i0 + k;
            if (i < n4u) {
                float4 v = ((const float4*)uemb)[i];
                ushort4 o;
                o.x = f2b(v.x); o.y = f2b(v.y); o.z = f2b(v.z); o.w = f2b(v.w);
                ((ushort4*)buB)[i] = o;
            }
        }
    }
}

// ---- MFMA transform: 128-node tiles, no LDS -------------------------------
// Wave w owns rows [tile*128 + w*32, +32). W (bf16, [64k][64h]) preloaded as
// 16 bf16x8 fragments per (A,S). X frags loaded direct from global (16B/lane).
// mfma_f32_16x16x32_bf16; C/D: col = lane&15, row = (lane>>4)*4 + reg (m89).

__device__ __forceinline__ void transform_tiles_mfma(
    int tile0, int stride, int ntiles,
    const unsigned short* __restrict__ X,
    const unsigned short* __restrict__ wA,   // bf16 [64][64] k-major
    const unsigned short* __restrict__ wS,
    const float* __restrict__ bS,
    unsigned short* __restrict__ A, unsigned short* __restrict__ S, int n) {
    int tid = threadIdx.x;
    int wave = tid >> 6, lane = tid & 63;
    int lrow = lane & 15;        // A row / B col / D col within 16
    int lkb  = lane >> 4;        // k-block (8 k each) / D row-block

    // ---- preload W fragments: [col-tile][k-step] ----
    bf16x8 fa[4][2], fs[4][2];
#pragma unroll
    for (int ct = 0; ct < 4; ++ct)
#pragma unroll
        for (int ksp = 0; ksp < 2; ++ksp) {
            int col = ct * 16 + lrow;
            int k0  = ksp * 32 + lkb * 8;
#pragma unroll
            for (int j = 0; j < 8; ++j) {
                fa[ct][ksp][j] = (short)wA[(k0 + j) * 64 + col];
                fs[ct][ksp][j] = (short)wS[(k0 + j) * 64 + col];
            }
        }
    float bias[4];
#pragma unroll
    for (int ct = 0; ct < 4; ++ct) bias[ct] = bS[ct * 16 + lrow];
    const bf16x8 zf = {0, 0, 0, 0, 0, 0, 0, 0};

    for (int tile = tile0; tile < ntiles; tile += stride) {
        int node0 = tile * 128 + wave * 32;
        bf16x8 xa[2][2];
#pragma unroll
        for (int rt = 0; rt < 2; ++rt) {
            int node = node0 + rt * 16 + lrow;
#pragma unroll
            for (int ksp = 0; ksp < 2; ++ksp) {
                xa[rt][ksp] = (node < n)
                    ? *(const bf16x8*)(X + (size_t)node * 64 + ksp * 32 + lkb * 8)
                    : zf;
            }
        }
#pragma unroll
        for (int rt = 0; rt < 2; ++rt) {
#pragma unroll
            for (int ct = 0; ct < 4; ++ct) {
                f32x4 accA = {0.f, 0.f, 0.f, 0.f}, accS = {0.f, 0.f, 0.f, 0.f};
                accA = __builtin_amdgcn_mfma_f32_16x16x32_bf16(xa[rt][0], fa[ct][0], accA, 0, 0, 0);
                accA = __builtin_amdgcn_mfma_f32_16x16x32_bf16(xa[rt][1], fa[ct][1], accA, 0, 0, 0);
                accS = __builtin_amdgcn_mfma_f32_16x16x32_bf16(xa[rt][0], fs[ct][0], accS, 0, 0, 0);
                accS = __builtin_amdgcn_mfma_f32_16x16x32_bf16(xa[rt][1], fs[ct][1], accS, 0, 0, 0);
#pragma unroll
                for (int r = 0; r < 4; ++r) {
                    int row = node0 + rt * 16 + lkb * 4 + r;
                    if (row < n) {
                        A[(size_t)row * 64 + ct * 16 + lrow] = f2b(accA[r]);
                        S[(size_t)row * 64 + ct * 16 + lrow] = f2b(accS[r] + bias[ct]);
                    }
                }
            }
        }
    }
}

// ---- fine CSR body --------------------------------------------------------

template <int NPB, int SH, typename CT>
__device__ __forceinline__ void fine_body(
    int b, int* c, int* sc, const int* __restrict__ part,
    const int* __restrict__ cnt_arr,
    int2* __restrict__ rp2, CT* __restrict__ col, int n) {
    int cnt = min(cnt_arr[b], BC);
    int pb = b * BC;
    int t = threadIdx.x;
    c[t] = 0;
    __syncthreads();
    const int mask = NPB - 1;
    for (int j = t; j < cnt; j += 256)
        atomicAdd(&c[part[pb + j] & mask], 1);
    __syncthreads();
    int own = c[t];
    sc[t] = own;
    __syncthreads();
    for (int off = 1; off < 256; off <<= 1) {
        int val = sc[t];
        int add = (t >= off) ? sc[t - off] : 0;
        __syncthreads();
        sc[t] = val + add;
        __syncthreads();
    }
    int start = pb + sc[t] - own;
    int node = b * NPB + t;
    if (t < NPB && node < n) rp2[node] = make_int2(start, start + own);
    __syncthreads();
    c[t] = start;
    __syncthreads();
    for (int j = t; j < cnt; j += 256) {
        int p = part[pb + j];
        int off = atomicAdd(&c[p & mask], 1);
        col[off] = (CT)(((unsigned)p) >> SH);
    }
}

#define TBM 256   // movie transform blocks
#define TBU 512   // user transform blocks

// ---- build_b: [0, nbm+nbu) fine CSR | +TBM movie transform | +TBU user ----

__global__ __launch_bounds__(256) void build_b(
    int nbm, int nbu, int ntm, int ntu,
    const int* __restrict__ pm, const int* __restrict__ cm,
    int2* __restrict__ rp2_m, int* __restrict__ col_m, int M,
    const int* __restrict__ pu, const int* __restrict__ cu,
    int2* __restrict__ rp2_u, unsigned short* __restrict__ col_u, int U,
    const unsigned short* __restrict__ xM, const unsigned short* __restrict__ wAM,
    const unsigned short* __restrict__ wSM, const float* __restrict__ bSM,
    unsigned short* __restrict__ AM, unsigned short* __restrict__ SM,
    const unsigned short* __restrict__ xU, const unsigned short* __restrict__ wAU,
    const unsigned short* __restrict__ wSU, const float* __restrict__ bSU,
    unsigned short* __restrict__ AU, unsigned short* __restrict__ SU) {
    __shared__ int cs[512];   // fine CSR counters + scan only (2 KB)
    int b = blockIdx.x;
    if (b < nbm) {
        fine_body<128, 7, int>(b, cs, cs + 256, pm, cm, rp2_m, col_m, M);
        return;
    }
    b -= nbm;
    if (b < nbu) {
        fine_body<256, 8, unsigned short>(b, cs, cs + 256, pu, cu, rp2_u, col_u, U);
        return;
    }
    b -= nbu;
    if (b < TBM) transform_tiles_mfma(b, TBM, ntm, xM, wAM, wSM, bSM, AM, SM, M);
    else transform_tiles_mfma(b - TBM, TBU, ntu, xU, wAU, wSU, bSU, AU, SU, U);
}

// ---- standalone transform (layer 1) ---------------------------------------

__global__ __launch_bounds__(256) void transform_dual(
    int ntm, int ntu,
    const unsigned short* __restrict__ xM, const unsigned short* __restrict__ wAM,
    const unsigned short* __restrict__ wSM, const float* __restrict__ bSM,
    unsigned short* __restrict__ AM, unsigned short* __restrict__ SM, int M,
    const unsigned short* __restrict__ xU, const unsigned short* __restrict__ wAU,
    const unsigned short* __restrict__ wSU, const float* __restrict__ bSU,
    unsigned short* __restrict__ AU, unsigned short* __restrict__ SU, int U) {
    int b = blockIdx.x;
    if (b < TBM) transform_tiles_mfma(b, TBM, ntm, xM, wAM, wSM, bSM, AM, SM, M);
    else transform_tiles_mfma(b - TBM, TBU, ntu, xU, wAU, wSU, bSU, AU, SU, U);
}

// ---- group-per-node gather: 8 groups x 8 lanes, 8 nodes/wave --------------
// Group g owns node (b*32 + wave*8 + g); lane q holds features q*8..q*8+7.
// Main loop identical economics to R19 (2 uint4 row loads in flight, 16
// independent chains); NO cross-lane reduction - lane stores its uint4.

template <typename CT>
__device__ __forceinline__ void gather_body(
    int b, const int2* __restrict__ rp2, const CT* __restrict__ col,
    const unsigned short* __restrict__ A, const unsigned short* __restrict__ S,
    unsigned short* __restrict__ out, int n, int do_relu) {
    int node = (b * 256 + (int)threadIdx.x) >> 3;   // one 8-lane group per node
    if (node >= n) return;
    int q = threadIdx.x & 7;                        // feature lane within group
    int2 be = rp2[node];
    int beg = be.x, end = be.y;
    float s0 = 0, s1 = 0, s2 = 0, s3 = 0, s4 = 0, s5 = 0, s6 = 0, s7 = 0;
    float t0 = 0, t1 = 0, t2 = 0, t3 = 0, t4 = 0, t5 = 0, t6 = 0, t7 = 0;
    int j = beg;
    for (; j + 1 < end; j += 2) {
        int n0 = (int)col[j], n1 = (int)col[j + 1];
        uint4 w0 = *(const uint4*)(A + (size_t)n0 * 64 + q * 8);
        uint4 w1 = *(const uint4*)(A + (size_t)n1 * 64 + q * 8);
        float2 p;
        p = bf2(w0.x); s0 += p.x; s1 += p.y;
        p = bf2(w0.y); s2 += p.x; s3 += p.y;
        p = bf2(w0.z); s4 += p.x; s5 += p.y;
        p = bf2(w0.w); s6 += p.x; s7 += p.y;
        p = bf2(w1.x); t0 += p.x; t1 += p.y;
        p = bf2(w1.y); t2 += p.x; t3 += p.y;
        p = bf2(w1.z); t4 += p.x; t5 += p.y;
        p = bf2(w1.w); t6 += p.x; t7 += p.y;
    }
    if (j < end) {
        int n0 = (int)col[j];
        uint4 w0 = *(const uint4*)(A + (size_t)n0 * 64 + q * 8);
        float2 p;
        p = bf2(w0.x); s0 += p.x; s1 += p.y;
        p = bf2(w0.y); s2 += p.x; s3 += p.y;
        p = bf2(w0.z); s4 += p.x; s5 += p.y;
        p = bf2(w0.w); s6 += p.x; s7 += p.y;
    }
    s0 += t0; s1 += t1; s2 += t2; s3 += t3;
    s4 += t4; s5 += t5; s6 += t6; s7 += t7;
    float inv = 1.0f / fmaxf((float)(end - beg), 1.0f);
    uint4 sv = *(const uint4*)(S + (size_t)node * 64 + q * 8);
    float2 c0 = bf2(sv.x), c1 = bf2(sv.y), c2 = bf2(sv.z), c3 = bf2(sv.w);
    float v0 = s0 * inv + c0.x, v1 = s1 * inv + c0.y;
    float v2 = s2 * inv + c1.x, v3 = s3 * inv + c1.y;
    float v4 = s4 * inv + c2.x, v5 = s5 * inv + c2.y;
    float v6 = s6 * inv + c3.x, v7 = s7 * inv + c3.y;
    if (do_relu) {
        v0 = fmaxf(v0, 0.f); v1 = fmaxf(v1, 0.f); v2 = fmaxf(v2, 0.f);
        v3 = fmaxf(v3, 0.f); v4 = fmaxf(v4, 0.f); v5 = fmaxf(v5, 0.f);
        v6 = fmaxf(v6, 0.f); v7 = fmaxf(v7, 0.f);
    }
    uint4 o;
    o.x = pk2(v0, v1); o.y = pk2(v2, v3); o.z = pk2(v4, v5); o.w = pk2(v6, v7);
    *(uint4*)(out + (size_t)node * 64 + q * 8) = o;
}

__global__ __launch_bounds__(256) void gather_dual(
    int gm,
    const int2* __restrict__ rp2_m, const int* __restrict__ col_m,
    const unsigned short* __restrict__ AU, const unsigned short* __restrict__ SM,
    unsigned short* __restrict__ outM, int M,
    const int2* __restrict__ rp2_u, const unsigned short* __restrict__ col_u,
    const unsigned short* __restrict__ AM, const unsigned short* __restrict__ SU,
    unsigned short* __restrict__ outU, int U, int do_relu) {
    int b = blockIdx.x;
    if (b < gm) gather_body<int>(b, rp2_m, col_m, AU, SM, outM, M, do_relu);
    else gather_body<unsigned short>(b - gm, rp2_u, col_u, AM, SU, outU, U, do_relu);
}

// ---- link head: 8 edges/wave, uint4 lanes ---------------------------------

__global__ __launch_bounds__(256) void dot_bf16(
    const int* __restrict__ ls, const int* __restrict__ ld,
    const unsigned short* __restrict__ xuB, const unsigned short* __restrict__ xmB,
    float* __restrict__ out, int L) {
    int t = blockIdx.x * 256 + threadIdx.x;
    int lane = t & 63;
    int sub = lane >> 3, q = lane & 7;
    int e = (t >> 6) * 8 + sub;
    if (e < L) {
        int u = ls[e], m = ld[e];
        uint4 a = *(const uint4*)(xuB + (size_t)u * 64 + q * 8);
        uint4 b = *(const uint4*)(xmB + (size_t)m * 64 + q * 8);
        float2 a0 = bf2(a.x), a1 = bf2(a.y), a2 = bf2(a.z), a3 = bf2(a.w);
        float2 b0 = bf2(b.x), b1 = bf2(b.y), b2 = bf2(b.z), b3 = bf2(b.w);
        float p = a0.x * b0.x + a0.y * b0.y + a1.x * b1.x + a1.y * b1.y
                + a2.x * b2.x + a2.y * b2.y + a3.x * b3.x + a3.y * b3.y;
#pragma unroll
        for (int off = 1; off < 8; off <<= 1) p += __shfl_xor(p, off, 64);
        if (q == 0) out[e] = p;
    }
}

// ---------------------------------------------------------------------------

extern "C" void kernel_launch(void* const* d_in, const int* in_sizes, int n_in,
                              void* d_out, int out_size, void* d_ws, size_t ws_size,
                              hipStream_t stream) {
    const float* movie_x   = (const float*)d_in[0];
    const float* user_emb  = (const float*)d_in[1];
    const float* movie_emb = (const float*)d_in[2];
    const float* mlw       = (const float*)d_in[3];
    const float* mlb       = (const float*)d_in[4];
    const float* llw       = (const float*)d_in[5];   // [2][2][64][64]
    const float* llb       = (const float*)d_in[6];   // [2][2][64]
    const float* lrw       = (const float*)d_in[7];   // [2][2][64][64]
    const int*   esrc      = (const int*)d_in[8];
    const int*   edst      = (const int*)d_in[9];
    const int*   lsrc      = (const int*)d_in[10];
    const int*   ldst      = (const int*)d_in[11];

    const int U = in_sizes[1] / 64;
    const int M = in_sizes[2] / 64;
    const int E = in_sizes[8];
    const int L = in_sizes[10];
    float* out = (float*)d_out;

    const size_t M64 = (size_t)M * 64, U64 = (size_t)U * 64;
    const int nbu = (U + 255) >> 8;   // 256-user buckets  (391)
    const int nbm = (M + 127) >> 7;   // 128-movie buckets (391)

    // ---- ws layout: 256 B-aligned regions, hot tables first ----
    char* base = (char*)d_ws;
    size_t off = 0;
    auto alloc = [&](size_t bytes) -> void* {
        off = (off + 255) & ~(size_t)255;
        void* p = base + off;
        off += bytes;
        return p;
    };
    unsigned short* bmB0 = (unsigned short*)alloc(M64 * 2);   // movie feat L0 bf16
    unsigned short* buB0 = (unsigned short*)alloc(U64 * 2);   // user feat L0 bf16
    unsigned short* A_m  = (unsigned short*)alloc(M64 * 2);   // bf16, gathered by users
    unsigned short* A_u  = (unsigned short*)alloc(U64 * 2);   // bf16, gathered by movies
    unsigned short* S_m  = (unsigned short*)alloc(M64 * 2);   // bf16 self term
    unsigned short* S_u  = (unsigned short*)alloc(U64 * 2);
    unsigned short* xm1  = (unsigned short*)alloc(M64 * 2);   // layer-0 movie out
    unsigned short* xu1  = (unsigned short*)alloc(U64 * 2);   // layer-0 user out
    unsigned short* wTlB = (unsigned short*)alloc(4 * 4096 * 2);  // bf16 W tables
    unsigned short* wTrB = (unsigned short*)alloc(4 * 4096 * 2);
    int2* rp2_m = (int2*)alloc((size_t)M * 8);
    int2* rp2_u = (int2*)alloc((size_t)U * 8);
    int* col_m = (int*)alloc((size_t)nbm * BC * 4);           // padded, user ids
    unsigned short* col_u = (unsigned short*)alloc((size_t)nbu * BC * 2);
    int* bfu = (int*)alloc(800 * 4);                          // ONE region: bfu|bfm
    int* bfm = bfu + 400;
    int* part_u = (int*)alloc((size_t)nbu * BC * 4);          // packed 24-bit
    int* part_m = (int*)alloc((size_t)nbm * BC * 4);
    // final tables alias the (dead-by-then) part buffers (contiguous, aligned):
    unsigned short* xm2 = (unsigned short*)part_u;            // [M,64] final movie
    unsigned short* xu2 = xm2 + M64;                          // [U,64] final user

    const int np    = (E + CHP - 1) / CHP;                    // dual-dir chunks
    const int cvtb  = (U * 16 / 4 + 255) / 256;               // 4 float4/thread
    const int ntm = (M + 127) / 128, ntu = (U + 127) / 128;   // 128-node tiles
    const int gm_g = (M * 8 + 255) / 256, gu_g = (U * 8 + 255) / 256;  // 8 lanes/node

    // ---- build_a: dual-dir register partition + prep (fused) ----
    hipMemsetAsync(bfu, 0, 800 * sizeof(int), stream);
    build_a<<<np + 1088 + cvtb, 256, 0, stream>>>(
        np, esrc, edst, E, nbu, nbm, bfu, bfm, part_u, part_m,
        movie_x, mlw, mlb, movie_emb, bmB0, M,
        llw, lrw, wTlB, wTrB, user_emb, buB0, U * 16);

    // ---- build_b: fine CSR + transform L0 (fused, MFMA) ----
    build_b<<<nbm + nbu + TBM + TBU, 256, 0, stream>>>(
        nbm, nbu, ntm, ntu,
        part_m, bfm, rp2_m, col_m, M,
        part_u, bfu, rp2_u, col_u, U,
        bmB0, wTlB + 1 * 4096, wTrB + 0 * 4096, llb + 0 * 64, A_m, S_m,
        buB0, wTlB + 0 * 4096, wTrB + 1 * 4096, llb + 1 * 64, A_u, S_u);

    // ---- layer 0 gather ----
    gather_dual<<<gm_g + gu_g, 256, 0, stream>>>(gm_g,
        rp2_m, col_m, A_u, S_m, xm1, M,
        rp2_u, col_u, A_m, S_u, xu1, U, 1);

    // ---- layer 1 ---- (A/S reused; part buffers now dead -> xm2/xu2)
    transform_dual<<<TBM + TBU, 256, 0, stream>>>(ntm, ntu,
        xm1, wTlB + 3 * 4096, wTrB + 2 * 4096, llb + 2 * 64, A_m, S_m, M,
        xu1, wTlB + 2 * 4096, wTrB + 3 * 4096, llb + 3 * 64, A_u, S_u, U);
    gather_dual<<<gm_g + gu_g, 256, 0, stream>>>(gm_g,
        rp2_m, col_m, A_u, S_m, xm2, M,
        rp2_u, col_u, A_m, S_u, xu2, U, 0);

    // ---- link head ----
    dot_bf16<<<(L + 31) / 32, 256, 0, stream>>>(lsrc, ldst, xu2, xm2, out, L);
}

// Round 13
// 342.833 us; speedup vs baseline: 1.5628x; 1.0332x over previous
//
#include <hip/hip_runtime.h>

// ---------------------------------------------------------------------------
// Round 32: resubmit of R30/R31 (two bench infra timeouts — never measured).
// Gather main loop unrolled to 4 rows in flight (MLP depth test).
//  R29 measured: 68.0us/dispatch, VALUBusy 33%, hbm 40%, occ 67% — mixed
//  latency/BW regime. Discriminating experiment: 4 col + 4 row loads per
//  iteration (was 2). If latency-exposed -> ~58us; if L3-BW-bound -> flat
//  (then next lever is byte reduction). Everything else identical to R29
//  (MFMA transform, group-per-node gather epilogue, fine CSR, dot).
// ---------------------------------------------------------------------------

#define CHP 4096  // edges per partition block (both directions)
#define BC 6144   // bucket capacity (E[cnt]=5120, sigma=72 -> 14-sigma margin)

typedef __attribute__((ext_vector_type(8))) short bf16x8;
typedef __attribute__((ext_vector_type(4))) float f32x4;

__device__ __forceinline__ float b2f(unsigned short u) {
    union { unsigned int i; float f; } v; v.i = ((unsigned int)u) << 16; return v.f;
}
__device__ __forceinline__ unsigned short f2b(float f) {
    union { float f; unsigned int i; } v; v.f = f;
    unsigned int i = v.i;
    return (unsigned short)((i + 0x7FFFu + ((i >> 16) & 1u)) >> 16);  // RNE
}
__device__ __forceinline__ float2 bf2(unsigned int w) {   // unpack 2 bf16
    union { unsigned int i; float f; } lo, hi;
    lo.i = w << 16; hi.i = w & 0xFFFF0000u;
    return make_float2(lo.f, hi.f);
}
__device__ __forceinline__ unsigned int pk2(float a, float b) {
    return (unsigned int)f2b(a) | ((unsigned int)f2b(b) << 16);
}

// ---- build_a: [0,np) dual-dir partition | movie_init | wt(bf16) | cvt -----

__global__ __launch_bounds__(256) void build_a(
    int np,
    const int* __restrict__ src, const int* __restrict__ dst, int E,
    int nbu, int nbm, int* __restrict__ bfu, int* __restrict__ bfm,
    int* __restrict__ pu, int* __restrict__ pm,
    const float* __restrict__ movie_x, const float* __restrict__ wm,
    const float* __restrict__ bm, const float* __restrict__ memb,
    unsigned short* __restrict__ xmB, int M,
    const float* __restrict__ llw, const float* __restrict__ lrw,
    unsigned short* __restrict__ wTlB, unsigned short* __restrict__ wTrB,
    const float* __restrict__ uemb, unsigned short* __restrict__ buB, int n4u) {
    __shared__ int2 stag[CHP];           // 32 KB ordered staging (per direction)
    __shared__ int hist[512];
    __shared__ int scn[512];
    __shared__ int gb[400];
    __shared__ int lst[400];
    int t = threadIdx.x;
    int b = blockIdx.x;
    if (b < np) {
        // ---- one chunk, both directions; edges held in registers ----
        int c0 = b * CHP, lim = min(c0 + CHP, E), cnt = lim - c0;
        int ks[16], vs[16];
#pragma unroll
        for (int i = 0; i < 16; ++i) {
            int e = c0 + t + i * 256;
            if (e < lim) { ks[i] = src[e]; vs[i] = dst[e]; }
            else { ks[i] = 0; vs[i] = 0; }
        }
        for (int dir = 0; dir < 2; ++dir) {
            const int NB = dir ? nbm : nbu;
            const int SHIFT = dir ? 7 : 8;
            int* bf = dir ? bfm : bfu;
            int* P  = dir ? pm  : pu;
            __syncthreads();   // protect stag/hist reuse from previous dir
            for (int i = t; i < 512; i += 256) hist[i] = 0;
            __syncthreads();
#pragma unroll
            for (int i = 0; i < 16; ++i) {
                if (t + i * 256 < cnt) {
                    int k = dir ? vs[i] : ks[i];
                    atomicAdd(&hist[k >> SHIFT], 1);
                }
            }
            __syncthreads();
            scn[t] = hist[t]; scn[t + 256] = hist[t + 256];
            __syncthreads();
            for (int off = 1; off < 512; off <<= 1) {
                int v0 = scn[t],  a0 = (t >= off) ? scn[t - off] : 0;
                int i1 = t + 256;
                int v1 = scn[i1], a1 = scn[i1 - off];
                __syncthreads();
                scn[t] = v0 + a0; scn[i1] = v1 + a1;
                __syncthreads();
            }
            for (int i = t; i < NB; i += 256) {
                int c = hist[i];
                lst[i] = scn[i] - c;
                int r = c ? atomicAdd(&bf[i], c) : 0;
                if (r < 0) r = 0;
                if (r + c > BC) r = BC - c;
                gb[i] = i * BC + r;
            }
            __syncthreads();
            for (int i = t; i < 512; i += 256) hist[i] = (i < NB) ? lst[i] : 0;
            __syncthreads();
#pragma unroll
            for (int i = 0; i < 16; ++i) {
                if (t + i * 256 < cnt) {
                    int k = dir ? vs[i] : ks[i];
                    int v = dir ? ks[i] : vs[i];
                    int bk = k >> SHIFT;
                    int pos = atomicAdd(&hist[bk], 1);
                    int packed = dir ? ((v << 7) | (k & 127)) : ((v << 8) | (k & 255));
                    stag[pos] = make_int2(packed, bk);
                }
            }
            __syncthreads();
            for (int j = t; j < cnt; j += 256) {
                int2 s = stag[j];
                P[gb[s.y] + (j - lst[s.y])] = s.x;
            }
        }
        return;
    }
    int lb = b - np;
    if (lb < 1024) {
        float* w_s = (float*)stag;   // 64*21 floats
        for (int i = t; i < 64 * 20; i += 256) {
            int h = i / 20, f = i % 20;
            w_s[h * 21 + f] = wm[i];
        }
        __syncthreads();
        int lane = t & 63;
        float bias = bm[lane];
        int nw = (1024 * 256) >> 6;
        int w  = (lb * 256 + t) >> 6;
        for (int m = w; m < M; m += nw) {
            float fv  = (lane < 20) ? movie_x[m * 20 + lane] : 0.0f;
            float acc = bias + memb[m * 64 + lane];
#pragma unroll
            for (int f = 0; f < 20; ++f) {
                float xv = __shfl(fv, f, 64);
                acc += xv * w_s[lane * 21 + f];
            }
            xmB[m * 64 + lane] = f2b(acc);
        }
    } else if (lb < 1088) {
        int i = (lb - 1024) * 256 + t;
        int s = i >> 12, rem = i & 4095, k = rem >> 6, h = rem & 63;
        wTlB[i] = f2b(llw[s * 4096 + h * 64 + k]);
        wTrB[i] = f2b(lrw[s * 4096 + h * 64 + k]);
    } else {
        int i0 = ((lb - 1088) * 256 + t) * 4;
#pragma unroll
        for (int k = 0; k < 4; ++k) {
            int i = i0 + k;
            if (i < n4u) {
                float4 v = ((const float4*)uemb)[i];
                ushort4 o;
                o.x = f2b(v.x); o.y = f2b(v.y); o.z = f2b(v.z); o.w = f2b(v.w);
                ((ushort4*)buB)[i] = o;
            }
        }
    }
}

// ---- MFMA transform: 128-node tiles, no LDS -------------------------------
// Wave w owns rows [tile*128 + w*32, +32). W (bf16, [64k][64h]) preloaded as
// 16 bf16x8 fragments per (A,S). X frags loaded direct from global (16B/lane).
// mfma_f32_16x16x32_bf16; C/D: col = lane&15, row = (lane>>4)*4 + reg (m89).

__device__ __forceinline__ void transform_tiles_mfma(
    int tile0, int stride, int ntiles,
    const unsigned short* __restrict__ X,
    const unsigned short* __restrict__ wA,   // bf16 [64][64] k-major
    const unsigned short* __restrict__ wS,
    const float* __restrict__ bS,
    unsigned short* __restrict__ A, unsigned short* __restrict__ S, int n) {
    int tid = threadIdx.x;
    int wave = tid >> 6, lane = tid & 63;
    int lrow = lane & 15;        // A row / B col / D col within 16
    int lkb  = lane >> 4;        // k-block (8 k each) / D row-block

    // ---- preload W fragments: [col-tile][k-step] ----
    bf16x8 fa[4][2], fs[4][2];
#pragma unroll
    for (int ct = 0; ct < 4; ++ct)
#pragma unroll
        for (int ksp = 0; ksp < 2; ++ksp) {
            int col = ct * 16 + lrow;
            int k0  = ksp * 32 + lkb * 8;
#pragma unroll
            for (int j = 0; j < 8; ++j) {
                fa[ct][ksp][j] = (short)wA[(k0 + j) * 64 + col];
                fs[ct][ksp][j] = (short)wS[(k0 + j) * 64 + col];
            }
        }
    float bias[4];
#pragma unroll
    for (int ct = 0; ct < 4; ++ct) bias[ct] = bS[ct * 16 + lrow];
    const bf16x8 zf = {0, 0, 0, 0, 0, 0, 0, 0};

    for (int tile = tile0; tile < ntiles; tile += stride) {
        int node0 = tile * 128 + wave * 32;
        bf16x8 xa[2][2];
#pragma unroll
        for (int rt = 0; rt < 2; ++rt) {
            int node = node0 + rt * 16 + lrow;
#pragma unroll
            for (int ksp = 0; ksp < 2; ++ksp) {
                xa[rt][ksp] = (node < n)
                    ? *(const bf16x8*)(X + (size_t)node * 64 + ksp * 32 + lkb * 8)
                    : zf;
            }
        }
#pragma unroll
        for (int rt = 0; rt < 2; ++rt) {
#pragma unroll
            for (int ct = 0; ct < 4; ++ct) {
                f32x4 accA = {0.f, 0.f, 0.f, 0.f}, accS = {0.f, 0.f, 0.f, 0.f};
                accA = __builtin_amdgcn_mfma_f32_16x16x32_bf16(xa[rt][0], fa[ct][0], accA, 0, 0, 0);
                accA = __builtin_amdgcn_mfma_f32_16x16x32_bf16(xa[rt][1], fa[ct][1], accA, 0, 0, 0);
                accS = __builtin_amdgcn_mfma_f32_16x16x32_bf16(xa[rt][0], fs[ct][0], accS, 0, 0, 0);
                accS = __builtin_amdgcn_mfma_f32_16x16x32_bf16(xa[rt][1], fs[ct][1], accS, 0, 0, 0);
#pragma unroll
                for (int r = 0; r < 4; ++r) {
                    int row = node0 + rt * 16 + lkb * 4 + r;
                    if (row < n) {
                        A[(size_t)row * 64 + ct * 16 + lrow] = f2b(accA[r]);
                        S[(size_t)row * 64 + ct * 16 + lrow] = f2b(accS[r] + bias[ct]);
                    }
                }
            }
        }
    }
}

// ---- fine CSR body --------------------------------------------------------

template <int NPB, int SH, typename CT>
__device__ __forceinline__ void fine_body(
    int b, int* c, int* sc, const int* __restrict__ part,
    const int* __restrict__ cnt_arr,
    int2* __restrict__ rp2, CT* __restrict__ col, int n) {
    int cnt = min(cnt_arr[b], BC);
    int pb = b * BC;
    int t = threadIdx.x;
    c[t] = 0;
    __syncthreads();
    const int mask = NPB - 1;
    for (int j = t; j < cnt; j += 256)
        atomicAdd(&c[part[pb + j] & mask], 1);
    __syncthreads();
    int own = c[t];
    sc[t] = own;
    __syncthreads();
    for (int off = 1; off < 256; off <<= 1) {
        int val = sc[t];
        int add = (t >= off) ? sc[t - off] : 0;
        __syncthreads();
        sc[t] = val + add;
        __syncthreads();
    }
    int start = pb + sc[t] - own;
    int node = b * NPB + t;
    if (t < NPB && node < n) rp2[node] = make_int2(start, start + own);
    __syncthreads();
    c[t] = start;
    __syncthreads();
    for (int j = t; j < cnt; j += 256) {
        int p = part[pb + j];
        int off = atomicAdd(&c[p & mask], 1);
        col[off] = (CT)(((unsigned)p) >> SH);
    }
}

#define TBM 256   // movie transform blocks
#define TBU 512   // user transform blocks

// ---- build_b: [0, nbm+nbu) fine CSR | +TBM movie transform | +TBU user ----

__global__ __launch_bounds__(256) void build_b(
    int nbm, int nbu, int ntm, int ntu,
    const int* __restrict__ pm, const int* __restrict__ cm,
    int2* __restrict__ rp2_m, int* __restrict__ col_m, int M,
    const int* __restrict__ pu, const int* __restrict__ cu,
    int2* __restrict__ rp2_u, unsigned short* __restrict__ col_u, int U,
    const unsigned short* __restrict__ xM, const unsigned short* __restrict__ wAM,
    const unsigned short* __restrict__ wSM, const float* __restrict__ bSM,
    unsigned short* __restrict__ AM, unsigned short* __restrict__ SM,
    const unsigned short* __restrict__ xU, const unsigned short* __restrict__ wAU,
    const unsigned short* __restrict__ wSU, const float* __restrict__ bSU,
    unsigned short* __restrict__ AU, unsigned short* __restrict__ SU) {
    __shared__ int cs[512];   // fine CSR counters + scan only (2 KB)
    int b = blockIdx.x;
    if (b < nbm) {
        fine_body<128, 7, int>(b, cs, cs + 256, pm, cm, rp2_m, col_m, M);
        return;
    }
    b -= nbm;
    if (b < nbu) {
        fine_body<256, 8, unsigned short>(b, cs, cs + 256, pu, cu, rp2_u, col_u, U);
        return;
    }
    b -= nbu;
    if (b < TBM) transform_tiles_mfma(b, TBM, ntm, xM, wAM, wSM, bSM, AM, SM, M);
    else transform_tiles_mfma(b - TBM, TBU, ntu, xU, wAU, wSU, bSU, AU, SU, U);
}

// ---- standalone transform (layer 1) ---------------------------------------

__global__ __launch_bounds__(256) void transform_dual(
    int ntm, int ntu,
    const unsigned short* __restrict__ xM, const unsigned short* __restrict__ wAM,
    const unsigned short* __restrict__ wSM, const float* __restrict__ bSM,
    unsigned short* __restrict__ AM, unsigned short* __restrict__ SM, int M,
    const unsigned short* __restrict__ xU, const unsigned short* __restrict__ wAU,
    const unsigned short* __restrict__ wSU, const float* __restrict__ bSU,
    unsigned short* __restrict__ AU, unsigned short* __restrict__ SU, int U) {
    int b = blockIdx.x;
    if (b < TBM) transform_tiles_mfma(b, TBM, ntm, xM, wAM, wSM, bSM, AM, SM, M);
    else transform_tiles_mfma(b - TBM, TBU, ntu, xU, wAU, wSU, bSU, AU, SU, U);
}

// ---- group-per-node gather: 8 groups x 8 lanes, 8 nodes/wave --------------
// Group g owns node; lane q holds features q*8..q*8+7. Main loop: 4 col
// loads + 4 uint4 row loads in flight per iteration (MLP depth 4), 16
// independent chains (w0,w2 -> s; w1,w3 -> t). No cross-lane reduction.

template <typename CT>
__device__ __forceinline__ void gather_body(
    int b, const int2* __restrict__ rp2, const CT* __restrict__ col,
    const unsigned short* __restrict__ A, const unsigned short* __restrict__ S,
    unsigned short* __restrict__ out, int n, int do_relu) {
    int node = (b * 256 + (int)threadIdx.x) >> 3;   // one 8-lane group per node
    if (node >= n) return;
    int q = threadIdx.x & 7;                        // feature lane within group
    int2 be = rp2[node];
    int beg = be.x, end = be.y;
    float s0 = 0, s1 = 0, s2 = 0, s3 = 0, s4 = 0, s5 = 0, s6 = 0, s7 = 0;
    float t0 = 0, t1 = 0, t2 = 0, t3 = 0, t4 = 0, t5 = 0, t6 = 0, t7 = 0;
    int j = beg;
    for (; j + 3 < end; j += 4) {
        int n0 = (int)col[j],     n1 = (int)col[j + 1];
        int n2 = (int)col[j + 2], n3 = (int)col[j + 3];
        uint4 w0 = *(const uint4*)(A + (size_t)n0 * 64 + q * 8);
        uint4 w1 = *(const uint4*)(A + (size_t)n1 * 64 + q * 8);
        uint4 w2 = *(const uint4*)(A + (size_t)n2 * 64 + q * 8);
        uint4 w3 = *(const uint4*)(A + (size_t)n3 * 64 + q * 8);
        float2 p;
        p = bf2(w0.x); s0 += p.x; s1 += p.y;
        p = bf2(w0.y); s2 += p.x; s3 += p.y;
        p = bf2(w0.z); s4 += p.x; s5 += p.y;
        p = bf2(w0.w); s6 += p.x; s7 += p.y;
        p = bf2(w1.x); t0 += p.x; t1 += p.y;
        p = bf2(w1.y); t2 += p.x; t3 += p.y;
        p = bf2(w1.z); t4 += p.x; t5 += p.y;
        p = bf2(w1.w); t6 += p.x; t7 += p.y;
        p = bf2(w2.x); s0 += p.x; s1 += p.y;
        p = bf2(w2.y); s2 += p.x; s3 += p.y;
        p = bf2(w2.z); s4 += p.x; s5 += p.y;
        p = bf2(w2.w); s6 += p.x; s7 += p.y;
        p = bf2(w3.x); t0 += p.x; t1 += p.y;
        p = bf2(w3.y); t2 += p.x; t3 += p.y;
        p = bf2(w3.z); t4 += p.x; t5 += p.y;
        p = bf2(w3.w); t6 += p.x; t7 += p.y;
    }
    for (; j < end; ++j) {
        int n0 = (int)col[j];
        uint4 w0 = *(const uint4*)(A + (size_t)n0 * 64 + q * 8);
        float2 p;
        p = bf2(w0.x); s0 += p.x; s1 += p.y;
        p = bf2(w0.y); s2 += p.x; s3 += p.y;
        p = bf2(w0.z); s4 += p.x; s5 += p.y;
        p = bf2(w0.w); s6 += p.x; s7 += p.y;
    }
    s0 += t0; s1 += t1; s2 += t2; s3 += t3;
    s4 += t4; s5 += t5; s6 += t6; s7 += t7;
    float inv = 1.0f / fmaxf((float)(end - beg), 1.0f);
    uint4 sv = *(const uint4*)(S + (size_t)node * 64 + q * 8);
    float2 c0 = bf2(sv.x), c1 = bf2(sv.y), c2 = bf2(sv.z), c3 = bf2(sv.w);
    float v0 = s0 * inv + c0.x, v1 = s1 * inv + c0.y;
    float v2 = s2 * inv + c1.x, v3 = s3 * inv + c1.y;
    float v4 = s4 * inv + c2.x, v5 = s5 * inv + c2.y;
    float v6 = s6 * inv + c3.x, v7 = s7 * inv + c3.y;
    if (do_relu) {
        v0 = fmaxf(v0, 0.f); v1 = fmaxf(v1, 0.f); v2 = fmaxf(v2, 0.f);
        v3 = fmaxf(v3, 0.f); v4 = fmaxf(v4, 0.f); v5 = fmaxf(v5, 0.f);
        v6 = fmaxf(v6, 0.f); v7 = fmaxf(v7, 0.f);
    }
    uint4 o;
    o.x = pk2(v0, v1); o.y = pk2(v2, v3); o.z = pk2(v4, v5); o.w = pk2(v6, v7);
    *(uint4*)(out + (size_t)node * 64 + q * 8) = o;
}

__global__ __launch_bounds__(256) void gather_dual(
    int gm,
    const int2* __restrict__ rp2_m, const int* __restrict__ col_m,
    const unsigned short* __restrict__ AU, const unsigned short* __restrict__ SM,
    unsigned short* __restrict__ outM, int M,
    const int2* __restrict__ rp2_u, const unsigned short* __restrict__ col_u,
    const unsigned short* __restrict__ AM, const unsigned short* __restrict__ SU,
    unsigned short* __restrict__ outU, int U, int do_relu) {
    int b = blockIdx.x;
    if (b < gm) gather_body<int>(b, rp2_m, col_m, AU, SM, outM, M, do_relu);
    else gather_body<unsigned short>(b - gm, rp2_u, col_u, AM, SU, outU, U, do_relu);
}

// ---- link head: 8 edges/wave, uint4 lanes ---------------------------------

__global__ __launch_bounds__(256) void dot_bf16(
    const int* __restrict__ ls, const int* __restrict__ ld,
    const unsigned short* __restrict__ xuB, const unsigned short* __restrict__ xmB,
    float* __restrict__ out, int L) {
    int t = blockIdx.x * 256 + threadIdx.x;
    int lane = t & 63;
    int sub = lane >> 3, q = lane & 7;
    int e = (t >> 6) * 8 + sub;
    if (e < L) {
        int u = ls[e], m = ld[e];
        uint4 a = *(const uint4*)(xuB + (size_t)u * 64 + q * 8);
        uint4 b = *(const uint4*)(xmB + (size_t)m * 64 + q * 8);
        float2 a0 = bf2(a.x), a1 = bf2(a.y), a2 = bf2(a.z), a3 = bf2(a.w);
        float2 b0 = bf2(b.x), b1 = bf2(b.y), b2 = bf2(b.z), b3 = bf2(b.w);
        float p = a0.x * b0.x + a0.y * b0.y + a1.x * b1.x + a1.y * b1.y
                + a2.x * b2.x + a2.y * b2.y + a3.x * b3.x + a3.y * b3.y;
#pragma unroll
        for (int off = 1; off < 8; off <<= 1) p += __shfl_xor(p, off, 64);
        if (q == 0) out[e] = p;
    }
}

// ---------------------------------------------------------------------------

extern "C" void kernel_launch(void* const* d_in, const int* in_sizes, int n_in,
                              void* d_out, int out_size, void* d_ws, size_t ws_size,
                              hipStream_t stream) {
    const float* movie_x   = (const float*)d_in[0];
    const float* user_emb  = (const float*)d_in[1];
    const float* movie_emb = (const float*)d_in[2];
    const float* mlw       = (const float*)d_in[3];
    const float* mlb       = (const float*)d_in[4];
    const float* llw       = (const float*)d_in[5];   // [2][2][64][64]
    const float* llb       = (const float*)d_in[6];   // [2][2][64]
    const float* lrw       = (const float*)d_in[7];   // [2][2][64][64]
    const int*   esrc      = (const int*)d_in[8];
    const int*   edst      = (const int*)d_in[9];
    const int*   lsrc      = (const int*)d_in[10];
    const int*   ldst      = (const int*)d_in[11];

    const int U = in_sizes[1] / 64;
    const int M = in_sizes[2] / 64;
    const int E = in_sizes[8];
    const int L = in_sizes[10];
    float* out = (float*)d_out;

    const size_t M64 = (size_t)M * 64, U64 = (size_t)U * 64;
    const int nbu = (U + 255) >> 8;   // 256-user buckets  (391)
    const int nbm = (M + 127) >> 7;   // 128-movie buckets (391)

    // ---- ws layout: 256 B-aligned regions, hot tables first ----
    char* base = (char*)d_ws;
    size_t off = 0;
    auto alloc = [&](size_t bytes) -> void* {
        off = (off + 255) & ~(size_t)255;
        void* p = base + off;
        off += bytes;
        return p;
    };
    unsigned short* bmB0 = (unsigned short*)alloc(M64 * 2);   // movie feat L0 bf16
    unsigned short* buB0 = (unsigned short*)alloc(U64 * 2);   // user feat L0 bf16
    unsigned short* A_m  = (unsigned short*)alloc(M64 * 2);   // bf16, gathered by users
    unsigned short* A_u  = (unsigned short*)alloc(U64 * 2);   // bf16, gathered by movies
    unsigned short* S_m  = (unsigned short*)alloc(M64 * 2);   // bf16 self term
    unsigned short* S_u  = (unsigned short*)alloc(U64 * 2);
    unsigned short* xm1  = (unsigned short*)alloc(M64 * 2);   // layer-0 movie out
    unsigned short* xu1  = (unsigned short*)alloc(U64 * 2);   // layer-0 user out
    unsigned short* wTlB = (unsigned short*)alloc(4 * 4096 * 2);  // bf16 W tables
    unsigned short* wTrB = (unsigned short*)alloc(4 * 4096 * 2);
    int2* rp2_m = (int2*)alloc((size_t)M * 8);
    int2* rp2_u = (int2*)alloc((size_t)U * 8);
    int* col_m = (int*)alloc((size_t)nbm * BC * 4);           // padded, user ids
    unsigned short* col_u = (unsigned short*)alloc((size_t)nbu * BC * 2);
    int* bfu = (int*)alloc(800 * 4);                          // ONE region: bfu|bfm
    int* bfm = bfu + 400;
    int* part_u = (int*)alloc((size_t)nbu * BC * 4);          // packed 24-bit
    int* part_m = (int*)alloc((size_t)nbm * BC * 4);
    // final tables alias the (dead-by-then) part buffers (contiguous, aligned):
    unsigned short* xm2 = (unsigned short*)part_u;            // [M,64] final movie
    unsigned short* xu2 = xm2 + M64;                          // [U,64] final user

    const int np    = (E + CHP - 1) / CHP;                    // dual-dir chunks
    const int cvtb  = (U * 16 / 4 + 255) / 256;               // 4 float4/thread
    const int ntm = (M + 127) / 128, ntu = (U + 127) / 128;   // 128-node tiles
    const int gm_g = (M * 8 + 255) / 256, gu_g = (U * 8 + 255) / 256;  // 8 lanes/node

    // ---- build_a: dual-dir register partition + prep (fused) ----
    hipMemsetAsync(bfu, 0, 800 * sizeof(int), stream);
    build_a<<<np + 1088 + cvtb, 256, 0, stream>>>(
        np, esrc, edst, E, nbu, nbm, bfu, bfm, part_u, part_m,
        movie_x, mlw, mlb, movie_emb, bmB0, M,
        llw, lrw, wTlB, wTrB, user_emb, buB0, U * 16);

    // ---- build_b: fine CSR + transform L0 (fused, MFMA) ----
    build_b<<<nbm + nbu + TBM + TBU, 256, 0, stream>>>(
        nbm, nbu, ntm, ntu,
        part_m, bfm, rp2_m, col_m, M,
        part_u, bfu, rp2_u, col_u, U,
        bmB0, wTlB + 1 * 4096, wTrB + 0 * 4096, llb + 0 * 64, A_m, S_m,
        buB0, wTlB + 0 * 4096, wTrB + 1 * 4096, llb + 1 * 64, A_u, S_u);

    // ---- layer 0 gather ----
    gather_dual<<<gm_g + gu_g, 256, 0, stream>>>(gm_g,
        rp2_m, col_m, A_u, S_m, xm1, M,
        rp2_u, col_u, A_m, S_u, xu1, U, 1);

    // ---- layer 1 ---- (A/S reused; part buffers now dead -> xm2/xu2)
    transform_dual<<<TBM + TBU, 256, 0, stream>>>(ntm, ntu,
        xm1, wTlB + 3 * 4096, wTrB + 2 * 4096, llb + 2 * 64, A_m, S_m, M,
        xu1, wTlB + 2 * 4096, wTrB + 3 * 4096, llb + 3 * 64, A_u, S_u, U);
    gather_dual<<<gm_g + gu_g, 256, 0, stream>>>(gm_g,
        rp2_m, col_m, A_u, S_m, xm2, M,
        rp2_u, col_u, A_m, S_u, xu2, U, 0);

    // ---- link head ----
    dot_bf16<<<(L + 31) / 32, 256, 0, stream>>>(lsrc, ldst, xu2, xm2, out, L);
}

// Round 16
// 333.361 us; speedup vs baseline: 1.6072x; 1.0284x over previous
//
#include <hip/hip_runtime.h>

// ---------------------------------------------------------------------------
// Round 35: resubmit of R33/R34 (two bench infra timeouts — never measured).
// Gather col-prefetch software pipeline (on top of R32's 4-deep).
//  R32 measured: 63.4us, VGPR 32, VALU 33%, hbm 44% — 4-deep unroll helped
//  (68->63.4) but col->row serial chain still exposes col latency each iter.
//  Single diff: preload cols one iteration ahead (rows issue, next cols
//  load, then unpack) — col latency hides under row latency. 16 independent
//  chains kept (R32-proven to preserve load batching).
//  Everything else identical to R32.
// ---------------------------------------------------------------------------

#define CHP 4096  // edges per partition block (both directions)
#define BC 6144   // bucket capacity (E[cnt]=5120, sigma=72 -> 14-sigma margin)

typedef __attribute__((ext_vector_type(8))) short bf16x8;
typedef __attribute__((ext_vector_type(4))) float f32x4;

__device__ __forceinline__ float b2f(unsigned short u) {
    union { unsigned int i; float f; } v; v.i = ((unsigned int)u) << 16; return v.f;
}
__device__ __forceinline__ unsigned short f2b(float f) {
    union { float f; unsigned int i; } v; v.f = f;
    unsigned int i = v.i;
    return (unsigned short)((i + 0x7FFFu + ((i >> 16) & 1u)) >> 16);  // RNE
}
__device__ __forceinline__ float2 bf2(unsigned int w) {   // unpack 2 bf16
    union { unsigned int i; float f; } lo, hi;
    lo.i = w << 16; hi.i = w & 0xFFFF0000u;
    return make_float2(lo.f, hi.f);
}
__device__ __forceinline__ unsigned int pk2(float a, float b) {
    return (unsigned int)f2b(a) | ((unsigned int)f2b(b) << 16);
}

// ---- build_a: [0,np) dual-dir partition | movie_init | wt(bf16) | cvt -----

__global__ __launch_bounds__(256) void build_a(
    int np,
    const int* __restrict__ src, const int* __restrict__ dst, int E,
    int nbu, int nbm, int* __restrict__ bfu, int* __restrict__ bfm,
    int* __restrict__ pu, int* __restrict__ pm,
    const float* __restrict__ movie_x, const float* __restrict__ wm,
    const float* __restrict__ bm, const float* __restrict__ memb,
    unsigned short* __restrict__ xmB, int M,
    const float* __restrict__ llw, const float* __restrict__ lrw,
    unsigned short* __restrict__ wTlB, unsigned short* __restrict__ wTrB,
    const float* __restrict__ uemb, unsigned short* __restrict__ buB, int n4u) {
    __shared__ int2 stag[CHP];           // 32 KB ordered staging (per direction)
    __shared__ int hist[512];
    __shared__ int scn[512];
    __shared__ int gb[400];
    __shared__ int lst[400];
    int t = threadIdx.x;
    int b = blockIdx.x;
    if (b < np) {
        // ---- one chunk, both directions; edges held in registers ----
        int c0 = b * CHP, lim = min(c0 + CHP, E), cnt = lim - c0;
        int ks[16], vs[16];
#pragma unroll
        for (int i = 0; i < 16; ++i) {
            int e = c0 + t + i * 256;
            if (e < lim) { ks[i] = src[e]; vs[i] = dst[e]; }
            else { ks[i] = 0; vs[i] = 0; }
        }
        for (int dir = 0; dir < 2; ++dir) {
            const int NB = dir ? nbm : nbu;
            const int SHIFT = dir ? 7 : 8;
            int* bf = dir ? bfm : bfu;
            int* P  = dir ? pm  : pu;
            __syncthreads();   // protect stag/hist reuse from previous dir
            for (int i = t; i < 512; i += 256) hist[i] = 0;
            __syncthreads();
#pragma unroll
            for (int i = 0; i < 16; ++i) {
                if (t + i * 256 < cnt) {
                    int k = dir ? vs[i] : ks[i];
                    atomicAdd(&hist[k >> SHIFT], 1);
                }
            }
            __syncthreads();
            scn[t] = hist[t]; scn[t + 256] = hist[t + 256];
            __syncthreads();
            for (int off = 1; off < 512; off <<= 1) {
                int v0 = scn[t],  a0 = (t >= off) ? scn[t - off] : 0;
                int i1 = t + 256;
                int v1 = scn[i1], a1 = scn[i1 - off];
                __syncthreads();
                scn[t] = v0 + a0; scn[i1] = v1 + a1;
                __syncthreads();
            }
            for (int i = t; i < NB; i += 256) {
                int c = hist[i];
                lst[i] = scn[i] - c;
                int r = c ? atomicAdd(&bf[i], c) : 0;
                if (r < 0) r = 0;
                if (r + c > BC) r = BC - c;
                gb[i] = i * BC + r;
            }
            __syncthreads();
            for (int i = t; i < 512; i += 256) hist[i] = (i < NB) ? lst[i] : 0;
            __syncthreads();
#pragma unroll
            for (int i = 0; i < 16; ++i) {
                if (t + i * 256 < cnt) {
                    int k = dir ? vs[i] : ks[i];
                    int v = dir ? ks[i] : vs[i];
                    int bk = k >> SHIFT;
                    int pos = atomicAdd(&hist[bk], 1);
                    int packed = dir ? ((v << 7) | (k & 127)) : ((v << 8) | (k & 255));
                    stag[pos] = make_int2(packed, bk);
                }
            }
            __syncthreads();
            for (int j = t; j < cnt; j += 256) {
                int2 s = stag[j];
                P[gb[s.y] + (j - lst[s.y])] = s.x;
            }
        }
        return;
    }
    int lb = b - np;
    if (lb < 1024) {
        float* w_s = (float*)stag;   // 64*21 floats
        for (int i = t; i < 64 * 20; i += 256) {
            int h = i / 20, f = i % 20;
            w_s[h * 21 + f] = wm[i];
        }
        __syncthreads();
        int lane = t & 63;
        float bias = bm[lane];
        int nw = (1024 * 256) >> 6;
        int w  = (lb * 256 + t) >> 6;
        for (int m = w; m < M; m += nw) {
            float fv  = (lane < 20) ? movie_x[m * 20 + lane] : 0.0f;
            float acc = bias + memb[m * 64 + lane];
#pragma unroll
            for (int f = 0; f < 20; ++f) {
                float xv = __shfl(fv, f, 64);
                acc += xv * w_s[lane * 21 + f];
            }
            xmB[m * 64 + lane] = f2b(acc);
        }
    } else if (lb < 1088) {
        int i = (lb - 1024) * 256 + t;
        int s = i >> 12, rem = i & 4095, k = rem >> 6, h = rem & 63;
        wTlB[i] = f2b(llw[s * 4096 + h * 64 + k]);
        wTrB[i] = f2b(lrw[s * 4096 + h * 64 + k]);
    } else {
        int i0 = ((lb - 1088) * 256 + t) * 4;
#pragma unroll
        for (int k = 0; k < 4; ++k) {
            int i = i0 + k;
            if (i < n4u) {
                float4 v = ((const float4*)uemb)[i];
                ushort4 o;
                o.x = f2b(v.x); o.y = f2b(v.y); o.z = f2b(v.z); o.w = f2b(v.w);
                ((ushort4*)buB)[i] = o;
            }
        }
    }
}

// ---- MFMA transform: 128-node tiles, no LDS -------------------------------
// Wave w owns rows [tile*128 + w*32, +32). W (bf16, [64k][64h]) preloaded as
// 16 bf16x8 fragments per (A,S). X frags loaded direct from global (16B/lane).
// mfma_f32_16x16x32_bf16; C/D: col = lane&15, row = (lane>>4)*4 + reg (m89).

__device__ __forceinline__ void transform_tiles_mfma(
    int tile0, int stride, int ntiles,
    const unsigned short* __restrict__ X,
    const unsigned short* __restrict__ wA,   // bf16 [64][64] k-major
    const unsigned short* __restrict__ wS,
    const float* __restrict__ bS,
    unsigned short* __restrict__ A, unsigned short* __restrict__ S, int n) {
    int tid = threadIdx.x;
    int wave = tid >> 6, lane = tid & 63;
    int lrow = lane & 15;        // A row / B col / D col within 16
    int lkb  = lane >> 4;        // k-block (8 k each) / D row-block

    // ---- preload W fragments: [col-tile][k-step] ----
    bf16x8 fa[4][2], fs[4][2];
#pragma unroll
    for (int ct = 0; ct < 4; ++ct)
#pragma unroll
        for (int ksp = 0; ksp < 2; ++ksp) {
            int col = ct * 16 + lrow;
            int k0  = ksp * 32 + lkb * 8;
#pragma unroll
            for (int j = 0; j < 8; ++j) {
                fa[ct][ksp][j] = (short)wA[(k0 + j) * 64 + col];
                fs[ct][ksp][j] = (short)wS[(k0 + j) * 64 + col];
            }
        }
    float bias[4];
#pragma unroll
    for (int ct = 0; ct < 4; ++ct) bias[ct] = bS[ct * 16 + lrow];
    const bf16x8 zf = {0, 0, 0, 0, 0, 0, 0, 0};

    for (int tile = tile0; tile < ntiles; tile += stride) {
        int node0 = tile * 128 + wave * 32;
        bf16x8 xa[2][2];
#pragma unroll
        for (int rt = 0; rt < 2; ++rt) {
            int node = node0 + rt * 16 + lrow;
#pragma unroll
            for (int ksp = 0; ksp < 2; ++ksp) {
                xa[rt][ksp] = (node < n)
                    ? *(const bf16x8*)(X + (size_t)node * 64 + ksp * 32 + lkb * 8)
                    : zf;
            }
        }
#pragma unroll
        for (int rt = 0; rt < 2; ++rt) {
#pragma unroll
            for (int ct = 0; ct < 4; ++ct) {
                f32x4 accA = {0.f, 0.f, 0.f, 0.f}, accS = {0.f, 0.f, 0.f, 0.f};
                accA = __builtin_amdgcn_mfma_f32_16x16x32_bf16(xa[rt][0], fa[ct][0], accA, 0, 0, 0);
                accA = __builtin_amdgcn_mfma_f32_16x16x32_bf16(xa[rt][1], fa[ct][1], accA, 0, 0, 0);
                accS = __builtin_amdgcn_mfma_f32_16x16x32_bf16(xa[rt][0], fs[ct][0], accS, 0, 0, 0);
                accS = __builtin_amdgcn_mfma_f32_16x16x32_bf16(xa[rt][1], fs[ct][1], accS, 0, 0, 0);
#pragma unroll
                for (int r = 0; r < 4; ++r) {
                    int row = node0 + rt * 16 + lkb * 4 + r;
                    if (row < n) {
                        A[(size_t)row * 64 + ct * 16 + lrow] = f2b(accA[r]);
                        S[(size_t)row * 64 + ct * 16 + lrow] = f2b(accS[r] + bias[ct]);
                    }
                }
            }
        }
    }
}

// ---- fine CSR body --------------------------------------------------------

template <int NPB, int SH, typename CT>
__device__ __forceinline__ void fine_body(
    int b, int* c, int* sc, const int* __restrict__ part,
    const int* __restrict__ cnt_arr,
    int2* __restrict__ rp2, CT* __restrict__ col, int n) {
    int cnt = min(cnt_arr[b], BC);
    int pb = b * BC;
    int t = threadIdx.x;
    c[t] = 0;
    __syncthreads();
    const int mask = NPB - 1;
    for (int j = t; j < cnt; j += 256)
        atomicAdd(&c[part[pb + j] & mask], 1);
    __syncthreads();
    int own = c[t];
    sc[t] = own;
    __syncthreads();
    for (int off = 1; off < 256; off <<= 1) {
        int val = sc[t];
        int add = (t >= off) ? sc[t - off] : 0;
        __syncthreads();
        sc[t] = val + add;
        __syncthreads();
    }
    int start = pb + sc[t] - own;
    int node = b * NPB + t;
    if (t < NPB && node < n) rp2[node] = make_int2(start, start + own);
    __syncthreads();
    c[t] = start;
    __syncthreads();
    for (int j = t; j < cnt; j += 256) {
        int p = part[pb + j];
        int off = atomicAdd(&c[p & mask], 1);
        col[off] = (CT)(((unsigned)p) >> SH);
    }
}

#define TBM 256   // movie transform blocks
#define TBU 512   // user transform blocks

// ---- build_b: [0, nbm+nbu) fine CSR | +TBM movie transform | +TBU user ----

__global__ __launch_bounds__(256) void build_b(
    int nbm, int nbu, int ntm, int ntu,
    const int* __restrict__ pm, const int* __restrict__ cm,
    int2* __restrict__ rp2_m, int* __restrict__ col_m, int M,
    const int* __restrict__ pu, const int* __restrict__ cu,
    int2* __restrict__ rp2_u, unsigned short* __restrict__ col_u, int U,
    const unsigned short* __restrict__ xM, const unsigned short* __restrict__ wAM,
    const unsigned short* __restrict__ wSM, const float* __restrict__ bSM,
    unsigned short* __restrict__ AM, unsigned short* __restrict__ SM,
    const unsigned short* __restrict__ xU, const unsigned short* __restrict__ wAU,
    const unsigned short* __restrict__ wSU, const float* __restrict__ bSU,
    unsigned short* __restrict__ AU, unsigned short* __restrict__ SU) {
    __shared__ int cs[512];   // fine CSR counters + scan only (2 KB)
    int b = blockIdx.x;
    if (b < nbm) {
        fine_body<128, 7, int>(b, cs, cs + 256, pm, cm, rp2_m, col_m, M);
        return;
    }
    b -= nbm;
    if (b < nbu) {
        fine_body<256, 8, unsigned short>(b, cs, cs + 256, pu, cu, rp2_u, col_u, U);
        return;
    }
    b -= nbu;
    if (b < TBM) transform_tiles_mfma(b, TBM, ntm, xM, wAM, wSM, bSM, AM, SM, M);
    else transform_tiles_mfma(b - TBM, TBU, ntu, xU, wAU, wSU, bSU, AU, SU, U);
}

// ---- standalone transform (layer 1) ---------------------------------------

__global__ __launch_bounds__(256) void transform_dual(
    int ntm, int ntu,
    const unsigned short* __restrict__ xM, const unsigned short* __restrict__ wAM,
    const unsigned short* __restrict__ wSM, const float* __restrict__ bSM,
    unsigned short* __restrict__ AM, unsigned short* __restrict__ SM, int M,
    const unsigned short* __restrict__ xU, const unsigned short* __restrict__ wAU,
    const unsigned short* __restrict__ wSU, const float* __restrict__ bSU,
    unsigned short* __restrict__ AU, unsigned short* __restrict__ SU, int U) {
    int b = blockIdx.x;
    if (b < TBM) transform_tiles_mfma(b, TBM, ntm, xM, wAM, wSM, bSM, AM, SM, M);
    else transform_tiles_mfma(b - TBM, TBU, ntu, xU, wAU, wSU, bSU, AU, SU, U);
}

// ---- group-per-node gather: 8 groups x 8 lanes, 8 nodes/wave --------------
// Group g owns node; lane q holds features q*8..q*8+7. Main loop: 4 rows in
// flight + NEXT iteration's cols prefetched while rows are in flight (col
// latency hides under row latency). 16 independent chains; no cross-lane
// reduction.

template <typename CT>
__device__ __forceinline__ void gather_body(
    int b, const int2* __restrict__ rp2, const CT* __restrict__ col,
    const unsigned short* __restrict__ A, const unsigned short* __restrict__ S,
    unsigned short* __restrict__ out, int n, int do_relu) {
    int node = (b * 256 + (int)threadIdx.x) >> 3;   // one 8-lane group per node
    if (node >= n) return;
    int q = threadIdx.x & 7;                        // feature lane within group
    int2 be = rp2[node];
    int beg = be.x, end = be.y;
    float s0 = 0, s1 = 0, s2 = 0, s3 = 0, s4 = 0, s5 = 0, s6 = 0, s7 = 0;
    float t0 = 0, t1 = 0, t2 = 0, t3 = 0, t4 = 0, t5 = 0, t6 = 0, t7 = 0;
    int j = beg;
    int nit = (end - beg) >> 2;
    if (nit > 0) {
        int n0 = (int)col[j], n1 = (int)col[j + 1];
        int n2 = (int)col[j + 2], n3 = (int)col[j + 3];
        for (int it = 0; it < nit; ++it) {
            uint4 w0 = *(const uint4*)(A + (size_t)n0 * 64 + q * 8);
            uint4 w1 = *(const uint4*)(A + (size_t)n1 * 64 + q * 8);
            uint4 w2 = *(const uint4*)(A + (size_t)n2 * 64 + q * 8);
            uint4 w3 = *(const uint4*)(A + (size_t)n3 * 64 + q * 8);
            j += 4;
            if (it + 1 < nit) {                      // prefetch next cols
                n0 = (int)col[j];     n1 = (int)col[j + 1];
                n2 = (int)col[j + 2]; n3 = (int)col[j + 3];
            }
            float2 p;
            p = bf2(w0.x); s0 += p.x; s1 += p.y;
            p = bf2(w0.y); s2 += p.x; s3 += p.y;
            p = bf2(w0.z); s4 += p.x; s5 += p.y;
            p = bf2(w0.w); s6 += p.x; s7 += p.y;
            p = bf2(w1.x); t0 += p.x; t1 += p.y;
            p = bf2(w1.y); t2 += p.x; t3 += p.y;
            p = bf2(w1.z); t4 += p.x; t5 += p.y;
            p = bf2(w1.w); t6 += p.x; t7 += p.y;
            p = bf2(w2.x); s0 += p.x; s1 += p.y;
            p = bf2(w2.y); s2 += p.x; s3 += p.y;
            p = bf2(w2.z); s4 += p.x; s5 += p.y;
            p = bf2(w2.w); s6 += p.x; s7 += p.y;
            p = bf2(w3.x); t0 += p.x; t1 += p.y;
            p = bf2(w3.y); t2 += p.x; t3 += p.y;
            p = bf2(w3.z); t4 += p.x; t5 += p.y;
            p = bf2(w3.w); t6 += p.x; t7 += p.y;
        }
    }
    for (; j < end; ++j) {
        int n0 = (int)col[j];
        uint4 w0 = *(const uint4*)(A + (size_t)n0 * 64 + q * 8);
        float2 p;
        p = bf2(w0.x); s0 += p.x; s1 += p.y;
        p = bf2(w0.y); s2 += p.x; s3 += p.y;
        p = bf2(w0.z); s4 += p.x; s5 += p.y;
        p = bf2(w0.w); s6 += p.x; s7 += p.y;
    }
    s0 += t0; s1 += t1; s2 += t2; s3 += t3;
    s4 += t4; s5 += t5; s6 += t6; s7 += t7;
    float inv = 1.0f / fmaxf((float)(end - beg), 1.0f);
    uint4 sv = *(const uint4*)(S + (size_t)node * 64 + q * 8);
    float2 c0 = bf2(sv.x), c1 = bf2(sv.y), c2 = bf2(sv.z), c3 = bf2(sv.w);
    float v0 = s0 * inv + c0.x, v1 = s1 * inv + c0.y;
    float v2 = s2 * inv + c1.x, v3 = s3 * inv + c1.y;
    float v4 = s4 * inv + c2.x, v5 = s5 * inv + c2.y;
    float v6 = s6 * inv + c3.x, v7 = s7 * inv + c3.y;
    if (do_relu) {
        v0 = fmaxf(v0, 0.f); v1 = fmaxf(v1, 0.f); v2 = fmaxf(v2, 0.f);
        v3 = fmaxf(v3, 0.f); v4 = fmaxf(v4, 0.f); v5 = fmaxf(v5, 0.f);
        v6 = fmaxf(v6, 0.f); v7 = fmaxf(v7, 0.f);
    }
    uint4 o;
    o.x = pk2(v0, v1); o.y = pk2(v2, v3); o.z = pk2(v4, v5); o.w = pk2(v6, v7);
    *(uint4*)(out + (size_t)node * 64 + q * 8) = o;
}

__global__ __launch_bounds__(256) void gather_dual(
    int gm,
    const int2* __restrict__ rp2_m, const int* __restrict__ col_m,
    const unsigned short* __restrict__ AU, const unsigned short* __restrict__ SM,
    unsigned short* __restrict__ outM, int M,
    const int2* __restrict__ rp2_u, const unsigned short* __restrict__ col_u,
    const unsigned short* __restrict__ AM, const unsigned short* __restrict__ SU,
    unsigned short* __restrict__ outU, int U, int do_relu) {
    int b = blockIdx.x;
    if (b < gm) gather_body<int>(b, rp2_m, col_m, AU, SM, outM, M, do_relu);
    else gather_body<unsigned short>(b - gm, rp2_u, col_u, AM, SU, outU, U, do_relu);
}

// ---- link head: 8 edges/wave, uint4 lanes ---------------------------------

__global__ __launch_bounds__(256) void dot_bf16(
    const int* __restrict__ ls, const int* __restrict__ ld,
    const unsigned short* __restrict__ xuB, const unsigned short* __restrict__ xmB,
    float* __restrict__ out, int L) {
    int t = blockIdx.x * 256 + threadIdx.x;
    int lane = t & 63;
    int sub = lane >> 3, q = lane & 7;
    int e = (t >> 6) * 8 + sub;
    if (e < L) {
        int u = ls[e], m = ld[e];
        uint4 a = *(const uint4*)(xuB + (size_t)u * 64 + q * 8);
        uint4 b = *(const uint4*)(xmB + (size_t)m * 64 + q * 8);
        float2 a0 = bf2(a.x), a1 = bf2(a.y), a2 = bf2(a.z), a3 = bf2(a.w);
        float2 b0 = bf2(b.x), b1 = bf2(b.y), b2 = bf2(b.z), b3 = bf2(b.w);
        float p = a0.x * b0.x + a0.y * b0.y + a1.x * b1.x + a1.y * b1.y
                + a2.x * b2.x + a2.y * b2.y + a3.x * b3.x + a3.y * b3.y;
#pragma unroll
        for (int off = 1; off < 8; off <<= 1) p += __shfl_xor(p, off, 64);
        if (q == 0) out[e] = p;
    }
}

// ---------------------------------------------------------------------------

extern "C" void kernel_launch(void* const* d_in, const int* in_sizes, int n_in,
                              void* d_out, int out_size, void* d_ws, size_t ws_size,
                              hipStream_t stream) {
    const float* movie_x   = (const float*)d_in[0];
    const float* user_emb  = (const float*)d_in[1];
    const float* movie_emb = (const float*)d_in[2];
    const float* mlw       = (const float*)d_in[3];
    const float* mlb       = (const float*)d_in[4];
    const float* llw       = (const float*)d_in[5];   // [2][2][64][64]
    const float* llb       = (const float*)d_in[6];   // [2][2][64]
    const float* lrw       = (const float*)d_in[7];   // [2][2][64][64]
    const int*   esrc      = (const int*)d_in[8];
    const int*   edst      = (const int*)d_in[9];
    const int*   lsrc      = (const int*)d_in[10];
    const int*   ldst      = (const int*)d_in[11];

    const int U = in_sizes[1] / 64;
    const int M = in_sizes[2] / 64;
    const int E = in_sizes[8];
    const int L = in_sizes[10];
    float* out = (float*)d_out;

    const size_t M64 = (size_t)M * 64, U64 = (size_t)U * 64;
    const int nbu = (U + 255) >> 8;   // 256-user buckets  (391)
    const int nbm = (M + 127) >> 7;   // 128-movie buckets (391)

    // ---- ws layout: 256 B-aligned regions, hot tables first ----
    char* base = (char*)d_ws;
    size_t off = 0;
    auto alloc = [&](size_t bytes) -> void* {
        off = (off + 255) & ~(size_t)255;
        void* p = base + off;
        off += bytes;
        return p;
    };
    unsigned short* bmB0 = (unsigned short*)alloc(M64 * 2);   // movie feat L0 bf16
    unsigned short* buB0 = (unsigned short*)alloc(U64 * 2);   // user feat L0 bf16
    unsigned short* A_m  = (unsigned short*)alloc(M64 * 2);   // bf16, gathered by users
    unsigned short* A_u  = (unsigned short*)alloc(U64 * 2);   // bf16, gathered by movies
    unsigned short* S_m  = (unsigned short*)alloc(M64 * 2);   // bf16 self term
    unsigned short* S_u  = (unsigned short*)alloc(U64 * 2);
    unsigned short* xm1  = (unsigned short*)alloc(M64 * 2);   // layer-0 movie out
    unsigned short* xu1  = (unsigned short*)alloc(U64 * 2);   // layer-0 user out
    unsigned short* wTlB = (unsigned short*)alloc(4 * 4096 * 2);  // bf16 W tables
    unsigned short* wTrB = (unsigned short*)alloc(4 * 4096 * 2);
    int2* rp2_m = (int2*)alloc((size_t)M * 8);
    int2* rp2_u = (int2*)alloc((size_t)U * 8);
    int* col_m = (int*)alloc((size_t)nbm * BC * 4);           // padded, user ids
    unsigned short* col_u = (unsigned short*)alloc((size_t)nbu * BC * 2);
    int* bfu = (int*)alloc(800 * 4);                          // ONE region: bfu|bfm
    int* bfm = bfu + 400;
    int* part_u = (int*)alloc((size_t)nbu * BC * 4);          // packed 24-bit
    int* part_m = (int*)alloc((size_t)nbm * BC * 4);
    // final tables alias the (dead-by-then) part buffers (contiguous, aligned):
    unsigned short* xm2 = (unsigned short*)part_u;            // [M,64] final movie
    unsigned short* xu2 = xm2 + M64;                          // [U,64] final user

    const int np    = (E + CHP - 1) / CHP;                    // dual-dir chunks
    const int cvtb  = (U * 16 / 4 + 255) / 256;               // 4 float4/thread
    const int ntm = (M + 127) / 128, ntu = (U + 127) / 128;   // 128-node tiles
    const int gm_g = (M * 8 + 255) / 256, gu_g = (U * 8 + 255) / 256;  // 8 lanes/node

    // ---- build_a: dual-dir register partition + prep (fused) ----
    hipMemsetAsync(bfu, 0, 800 * sizeof(int), stream);
    build_a<<<np + 1088 + cvtb, 256, 0, stream>>>(
        np, esrc, edst, E, nbu, nbm, bfu, bfm, part_u, part_m,
        movie_x, mlw, mlb, movie_emb, bmB0, M,
        llw, lrw, wTlB, wTrB, user_emb, buB0, U * 16);

    // ---- build_b: fine CSR + transform L0 (fused, MFMA) ----
    build_b<<<nbm + nbu + TBM + TBU, 256, 0, stream>>>(
        nbm, nbu, ntm, ntu,
        part_m, bfm, rp2_m, col_m, M,
        part_u, bfu, rp2_u, col_u, U,
        bmB0, wTlB + 1 * 4096, wTrB + 0 * 4096, llb + 0 * 64, A_m, S_m,
        buB0, wTlB + 0 * 4096, wTrB + 1 * 4096, llb + 1 * 64, A_u, S_u);

    // ---- layer 0 gather ----
    gather_dual<<<gm_g + gu_g, 256, 0, stream>>>(gm_g,
        rp2_m, col_m, A_u, S_m, xm1, M,
        rp2_u, col_u, A_m, S_u, xu1, U, 1);

    // ---- layer 1 ---- (A/S reused; part buffers now dead -> xm2/xu2)
    transform_dual<<<TBM + TBU, 256, 0, stream>>>(ntm, ntu,
        xm1, wTlB + 3 * 4096, wTrB + 2 * 4096, llb + 2 * 64, A_m, S_m, M,
        xu1, wTlB + 2 * 4096, wTrB + 3 * 4096, llb + 3 * 64, A_u, S_u, U);
    gather_dual<<<gm_g + gu_g, 256, 0, stream>>>(gm_g,
        rp2_m, col_m, A_u, S_m, xm2, M,
        rp2_u, col_u, A_m, S_u, xu2, U, 0);

    // ---- link head ----
    dot_bf16<<<(L + 31) / 32, 256, 0, stream>>>(lsrc, ldst, xu2, xm2, out, L);
}